// Round 2
// baseline (6055.213 us; speedup 1.0000x reference)
//
#include <hip/hip_runtime.h>
#include <math.h>

#define EPS 1e-5f

constexpr int Bc = 32, Cc = 256, Hc = 56, Wc = 56;
constexpr int NHc = 8, HDc = 32, WSc = 7, SSc = 3;
constexpr int NTOK = 49;           // tokens per window
constexpr int NWIN = 64;           // windows per image (8x8)
constexpr int Lc = Hc * Wc;        // 3136
constexpr int Mrows = Bc * NWIN * NTOK;  // 100352
constexpr int GIMG = 4;            // images per processing group
constexpr int NGRP = Bc / GIMG;    // 8 groups
constexpr int ROWS_G = GIMG * Lc;  // 12544 rows per group
constexpr int WIN_G = GIMG * NWIN; // 256 windows per group

__device__ __forceinline__ float bf2f(unsigned short u) {
    return __uint_as_float(((unsigned)u) << 16);
}
__device__ __forceinline__ unsigned short f2bf(float f) {
    unsigned x = __float_as_uint(f);
    return (unsigned short)((x + 0x7fffu + ((x >> 16) & 1u)) >> 16);  // RNE
}

// ---------------------------------------------------------------- qkv bias
__global__ __launch_bounds__(256) void k_qkv_bias(const float* __restrict__ qb,
                                                  const float* __restrict__ vb,
                                                  float* __restrict__ out) {
    int t = threadIdx.x;
    out[t]       = qb[t];
    out[256 + t] = 0.f;
    out[512 + t] = vb[t];
}

// ---------------------------------------------- LN1 + roll(-3,-3) + window partition -> bf16
// grid: (B*H) blocks, 256 threads. xw[(b*64 + wh*8 + ww)*49 + th*7+tw][c] (bf16)
__global__ __launch_bounds__(256) void k_ln1_part(const float* __restrict__ x,
                                                  const float* __restrict__ n1w,
                                                  const float* __restrict__ n1b,
                                                  unsigned short* __restrict__ xw) {
    __shared__ float s[Cc * 57];
    __shared__ float mu[Wc], rs[Wc];
    int b = blockIdx.x / Hc, h = blockIdx.x % Hc;
    int t = threadIdx.x;
    const float* xp = x + ((size_t)b * Cc) * Lc + h * Wc;
    for (int idx = t; idx < Cc * Wc; idx += 256) {
        int c = idx / Wc, w = idx % Wc;
        s[c * 57 + w] = xp[(size_t)c * Lc + w];
    }
    __syncthreads();
    int lane = t & 63, wv = t >> 6;
    for (int p = wv; p < Wc; p += 4) {
        float sum = 0.f, sq = 0.f;
        #pragma unroll
        for (int k = 0; k < 4; ++k) {
            float v = s[(lane + 64 * k) * 57 + p];
            sum += v; sq += v * v;
        }
        #pragma unroll
        for (int off = 32; off; off >>= 1) {
            sum += __shfl_xor(sum, off);
            sq  += __shfl_xor(sq, off);
        }
        if (lane == 0) {
            float m = sum / Cc;
            mu[p] = m;
            rs[p] = rsqrtf(sq / Cc - m * m + EPS);
        }
    }
    __syncthreads();
    float wc_ = n1w[t], bc_ = n1b[t];
    int hr = (h + Hc - SSc) % Hc;
    int whh = hr / WSc, th = hr % WSc;
    for (int p = 0; p < Wc; ++p) {
        int wr = (p + Wc - SSc) % Wc;
        int www = wr / WSc, tw = wr % WSc;
        int row = (b * NWIN + whh * 8 + www) * NTOK + th * WSc + tw;
        float v = (s[t * 57 + p] - mu[p]) * rs[p] * wc_ + bc_;
        xw[(size_t)row * Cc + t] = f2bf(v);
    }
}

// ---------------------------------------------- GEMM: out = A @ W^T + bias (fp32 acc)
// A: (M,K) row-major (bf16 or fp32), W: (N,K) fp32 row-major, out fp32 (M,N).
template <bool ABF16>
__global__ __launch_bounds__(256) void k_gemm_nt(const void* __restrict__ Av,
                                                 const float* __restrict__ W,
                                                 const float* __restrict__ bias,
                                                 float* __restrict__ out,
                                                 int K, int Nd) {
    __shared__ float As[16][64];
    __shared__ float Bs[16][64];
    int t = threadIdx.x;
    int tx = t & 15, ty = t >> 4;
    int m0 = blockIdx.x * 64, n0 = blockIdx.y * 64;
    int lrow = t >> 2, lk = (t & 3) << 2;
    const float* Wp = W + (size_t)(n0 + lrow) * K + lk;
    float acc[4][4] = {};
    for (int kt = 0; kt < K; kt += 16) {
        float ax, ay, az, aw;
        if (ABF16) {
            const unsigned short* Ap =
                (const unsigned short*)Av + (size_t)(m0 + lrow) * K + lk + kt;
            ushort4 av = *(const ushort4*)Ap;
            ax = bf2f(av.x); ay = bf2f(av.y); az = bf2f(av.z); aw = bf2f(av.w);
        } else {
            const float* Ap = (const float*)Av + (size_t)(m0 + lrow) * K + lk + kt;
            float4 av = *(const float4*)Ap;
            ax = av.x; ay = av.y; az = av.z; aw = av.w;
        }
        float4 wv = *(const float4*)(Wp + kt);
        As[lk + 0][lrow] = ax; As[lk + 1][lrow] = ay;
        As[lk + 2][lrow] = az; As[lk + 3][lrow] = aw;
        Bs[lk + 0][lrow] = wv.x; Bs[lk + 1][lrow] = wv.y;
        Bs[lk + 2][lrow] = wv.z; Bs[lk + 3][lrow] = wv.w;
        __syncthreads();
        #pragma unroll
        for (int kk = 0; kk < 16; ++kk) {
            float a[4], bb[4];
            #pragma unroll
            for (int i = 0; i < 4; ++i) a[i] = As[kk][ty * 4 + i];
            #pragma unroll
            for (int j = 0; j < 4; ++j) bb[j] = Bs[kk][tx * 4 + j];
            #pragma unroll
            for (int i = 0; i < 4; ++i)
                #pragma unroll
                for (int j = 0; j < 4; ++j)
                    acc[i][j] += a[i] * bb[j];
        }
        __syncthreads();
    }
    float bj[4];
    #pragma unroll
    for (int j = 0; j < 4; ++j) bj[j] = bias[n0 + tx * 4 + j];
    #pragma unroll
    for (int i = 0; i < 4; ++i) {
        float4 o;
        o.x = acc[i][0] + bj[0];
        o.y = acc[i][1] + bj[1];
        o.z = acc[i][2] + bj[2];
        o.w = acc[i][3] + bj[3];
        *(float4*)&out[(size_t)(m0 + ty * 4 + i) * Nd + n0 + tx * 4] = o;
    }
}

// ---------------------------------------------- window attention, one block per (local window, head)
// qkv: fp32 (ROWS_G, 768) for this group; outb: bf16 (ROWS_G, 256) for this group.
__global__ __launch_bounds__(256) void k_attn(const float* __restrict__ qkv,
                                              const float* __restrict__ rpb,
                                              unsigned short* __restrict__ outb) {
    __shared__ float qs[NTOK * HDc];   // scaled q [i][d]
    __shared__ float kt[HDc * NTOK];   // k transposed [d][j]
    __shared__ float vs[NTOK * HDc];   // v [j][d]
    __shared__ float S[NTOK * NTOK];
    __shared__ int rid[NTOK];
    int bid = blockIdx.x;
    int b_ = bid >> 3, hh = bid & 7;   // b_ = local window in [0, WIN_G)
    int t = threadIdx.x;
    const float scale = 0.17677669529663687f;  // 32^-0.5
    const float* base = qkv + (size_t)b_ * NTOK * 768 + hh * HDc;
    for (int idx = t; idx < NTOK * HDc; idx += 256) {
        int n = idx >> 5, d = idx & 31;
        const float* r = base + n * 768 + d;
        qs[idx] = r[0] * scale;
        kt[d * NTOK + n] = r[256];
        vs[idx] = r[512];
    }
    if (t < NTOK) {
        int wi = b_ & 63;              // window index within its image
        int wh = wi >> 3, ww = wi & 7;
        int gh = wh * 7 + t / 7, gw = ww * 7 + t % 7;   // rolled-frame coords
        int rh = gh < 49 ? 0 : (gh < 53 ? 1 : 2);
        int rw = gw < 49 ? 0 : (gw < 53 ? 1 : 2);
        rid[t] = rh * 3 + rw;
    }
    __syncthreads();
    for (int idx = t; idx < NTOK * NTOK; idx += 256) {
        int i = idx / NTOK, j = idx % NTOK;
        float dot = 0.f;
        #pragma unroll 8
        for (int d = 0; d < HDc; ++d)
            dot += qs[i * HDc + d] * kt[d * NTOK + j];
        int ih = i / 7, iw = i % 7, jh = j / 7, jw = j % 7;
        int rpi = (ih - jh + 6) * 13 + (iw - jw + 6);
        float bv = rpb[rpi * NHc + hh];
        float m = (rid[i] == rid[j]) ? 0.f : -100.f;
        S[idx] = dot + bv + m;
    }
    __syncthreads();
    int lane = t & 63, wv = t >> 6;
    for (int r = wv; r < NTOK; r += 4) {
        float v = (lane < NTOK) ? S[r * NTOK + lane] : -1e30f;
        float mx = v;
        #pragma unroll
        for (int off = 32; off; off >>= 1) mx = fmaxf(mx, __shfl_xor(mx, off));
        float e = (lane < NTOK) ? __expf(v - mx) : 0.f;
        float sum = e;
        #pragma unroll
        for (int off = 32; off; off >>= 1) sum += __shfl_xor(sum, off);
        if (lane < NTOK) S[r * NTOK + lane] = e / sum;
    }
    __syncthreads();
    for (int idx = t; idx < NTOK * HDc; idx += 256) {
        int i = idx >> 5, d = idx & 31;
        float acc = 0.f;
        #pragma unroll 7
        for (int j = 0; j < NTOK; ++j)
            acc += S[i * NTOK + j] * vs[j * HDc + d];
        outb[((size_t)b_ * NTOK + i) * Cc + hh * HDc + d] = f2bf(acc);
    }
}

// ---------------------------------------------- window-reverse + unshift + residual -> bf16 xs
// pj: fp32 (ROWS_G, 256) local rows; x global; b0 = first image of group.
__global__ __launch_bounds__(256) void k_scatter(const float* __restrict__ x,
                                                 const float* __restrict__ pj,
                                                 unsigned short* __restrict__ xs,
                                                 int b0) {
    __shared__ float s[Cc * 57];
    int bg = blockIdx.x / Hc, h = blockIdx.x % Hc;
    int b = b0 + bg;
    int t = threadIdx.x;
    const float* xp = x + ((size_t)b * Cc) * Lc + h * Wc;
    for (int idx = t; idx < Cc * Wc; idx += 256) {
        int c = idx / Wc, w = idx % Wc;
        s[c * 57 + w] = xp[(size_t)c * Lc + w];
    }
    __syncthreads();
    int hr = (h + Hc - SSc) % Hc;
    int whh = hr / WSc, th = hr % WSc;
    for (int p = 0; p < Wc; ++p) {
        int wr = (p + Wc - SSc) % Wc;
        int row = (bg * NWIN + whh * 8 + wr / WSc) * NTOK + th * WSc + (wr % WSc);
        xs[((size_t)b * Lc + h * Wc + p) * Cc + t] =
            f2bf(s[t * 57 + p] + pj[(size_t)row * Cc + t]);
    }
}

// ---------------------------------------------- LN2 + MLP + residual + NCHW out (fp32)
__global__ __launch_bounds__(256) void k_mlp(const unsigned short* __restrict__ xs,
                                             const float* __restrict__ n2w,
                                             const float* __restrict__ n2b,
                                             const float* __restrict__ w1,
                                             const float* __restrict__ b1,
                                             const float* __restrict__ w2,
                                             const float* __restrict__ b2,
                                             float* __restrict__ out) {
    constexpr int R = 8;
    __shared__ float xsr[R * Cc];
    __shared__ float xn[R * Cc];
    __shared__ float hid[R * 1024];
    int m0 = blockIdx.x * R;
    int t = threadIdx.x;
    const unsigned short* xp = xs + (size_t)m0 * Cc;
    for (int idx = t; idx < R * Cc / 4; idx += 256) {
        ushort4 u = ((const ushort4*)xp)[idx];
        xsr[idx * 4 + 0] = bf2f(u.x);
        xsr[idx * 4 + 1] = bf2f(u.y);
        xsr[idx * 4 + 2] = bf2f(u.z);
        xsr[idx * 4 + 3] = bf2f(u.w);
    }
    __syncthreads();
    int lane = t & 63, wv = t >> 6;
    #pragma unroll
    for (int rr = 0; rr < 2; ++rr) {
        int r = wv * 2 + rr;
        float sum = 0.f, sq = 0.f;
        #pragma unroll
        for (int k = 0; k < 4; ++k) {
            float v = xsr[r * Cc + lane + 64 * k];
            sum += v; sq += v * v;
        }
        #pragma unroll
        for (int off = 32; off; off >>= 1) {
            sum += __shfl_xor(sum, off);
            sq  += __shfl_xor(sq, off);
        }
        float m = sum / Cc;
        float rsg = rsqrtf(sq / Cc - m * m + EPS);
        #pragma unroll
        for (int k = 0; k < 4; ++k) {
            int c = lane + 64 * k;
            xn[r * Cc + c] = (xsr[r * Cc + c] - m) * rsg * n2w[c] + n2b[c];
        }
    }
    __syncthreads();
    // fc1 + relu
    {
        float acc[4][R];
        #pragma unroll
        for (int c = 0; c < 4; ++c) {
            float bv = b1[c * 256 + t];
            #pragma unroll
            for (int r = 0; r < R; ++r) acc[c][r] = bv;
        }
        for (int k4 = 0; k4 < Cc; k4 += 4) {
            float4 xv[R];
            #pragma unroll
            for (int r = 0; r < R; ++r) xv[r] = *(const float4*)&xn[r * Cc + k4];
            #pragma unroll
            for (int c = 0; c < 4; ++c) {
                float4 w4 = *(const float4*)&w1[(size_t)(c * 256 + t) * Cc + k4];
                #pragma unroll
                for (int r = 0; r < R; ++r)
                    acc[c][r] += xv[r].x * w4.x + xv[r].y * w4.y + xv[r].z * w4.z + xv[r].w * w4.w;
            }
        }
        #pragma unroll
        for (int c = 0; c < 4; ++c)
            #pragma unroll
            for (int r = 0; r < R; ++r)
                hid[r * 1024 + c * 256 + t] = fmaxf(acc[c][r], 0.f);
    }
    __syncthreads();
    // fc2 + residual
    {
        float acc2[R];
        float bv = b2[t];
        #pragma unroll
        for (int r = 0; r < R; ++r) acc2[r] = bv;
        for (int o4 = 0; o4 < 1024; o4 += 4) {
            float4 w4 = *(const float4*)&w2[(size_t)t * 1024 + o4];
            #pragma unroll
            for (int r = 0; r < R; ++r) {
                float4 hv = *(const float4*)&hid[r * 1024 + o4];
                acc2[r] += hv.x * w4.x + hv.y * w4.y + hv.z * w4.z + hv.w * w4.w;
            }
        }
        #pragma unroll
        for (int r = 0; r < R; ++r)
            xn[r * Cc + t] = xsr[r * Cc + t] + acc2[r];
    }
    __syncthreads();
    int b = m0 / Lc, l0 = m0 % Lc;
    int rr = t & 7, cb = t >> 3;
    for (int chunk = 0; chunk < 8; ++chunk) {
        int c = cb + 32 * chunk;
        out[((size_t)b * Cc + c) * Lc + l0 + rr] = xn[rr * Cc + c];
    }
}

// ----------------------------------------------------------------- launch
extern "C" void kernel_launch(void* const* d_in, const int* in_sizes, int n_in,
                              void* d_out, int out_size, void* d_ws, size_t ws_size,
                              hipStream_t stream) {
    const float* x      = (const float*)d_in[0];
    const float* qkv_w  = (const float*)d_in[1];
    const float* q_bias = (const float*)d_in[2];
    const float* v_bias = (const float*)d_in[3];
    const float* proj_w = (const float*)d_in[4];
    const float* proj_b = (const float*)d_in[5];
    const float* rpb    = (const float*)d_in[6];
    const float* n1w    = (const float*)d_in[7];
    const float* n1b    = (const float*)d_in[8];
    const float* n2w    = (const float*)d_in[9];
    const float* n2b    = (const float*)d_in[10];
    const float* w1     = (const float*)d_in[11];
    const float* b1     = (const float*)d_in[12];
    const float* w2     = (const float*)d_in[13];
    const float* b2     = (const float*)d_in[14];

    // Workspace: only bf16 xw/xs stream (51.38 MB) + qkv bias (3 KB).
    const size_t SZ_BF16 = (size_t)Mrows * Cc * 2;   // 51,380,224 B
    unsigned short* xw = (unsigned short*)d_ws;       // xw, later reused as xs
    float* qkvb = (float*)((char*)d_ws + SZ_BF16);

    // d_out doubles as scratch until the final MLP pass overwrites all of it:
    //   [0, 51.38MB)           attn_out bf16 (all rows)
    //   [51.38MB, 89.92MB)     per-group fp32 buffer: qkv (12544x768), then proj_out (12544x256)
    unsigned short* attn_lo = (unsigned short*)d_out;
    float* scratch2 = (float*)((char*)d_out + SZ_BF16);

    k_qkv_bias<<<1, 256, 0, stream>>>(q_bias, v_bias, qkvb);
    k_ln1_part<<<Bc * Hc, 256, 0, stream>>>(x, n1w, n1b, xw);

    for (int g = 0; g < NGRP; ++g) {
        const unsigned short* xw_g = xw + (size_t)g * ROWS_G * Cc;
        unsigned short* attn_g = attn_lo + (size_t)g * ROWS_G * Cc;
        // qkv chunk: (ROWS_G, 768) fp32
        k_gemm_nt<true><<<dim3(ROWS_G / 64, 768 / 64), 256, 0, stream>>>(
            (const void*)xw_g, qkv_w, qkvb, scratch2, 256, 768);
        k_attn<<<WIN_G * NHc, 256, 0, stream>>>(scratch2, rpb, attn_g);
        // proj chunk: (ROWS_G, 256) fp32 — reuses scratch2 (qkv dead)
        k_gemm_nt<true><<<dim3(ROWS_G / 64, 256 / 64), 256, 0, stream>>>(
            (const void*)attn_g, proj_w, proj_b, scratch2, 256, 256);
        k_scatter<<<GIMG * Hc, 256, 0, stream>>>(x, scratch2, xw, g * GIMG);
    }

    k_mlp<<<Mrows / 8, 256, 0, stream>>>(xw, n2w, n2b, w1, b1, w2, b2, (float*)d_out);
}

// Round 3
// 1182.362 us; speedup vs baseline: 5.1213x; 5.1213x over previous
//
#include <hip/hip_runtime.h>
#include <math.h>

#define EPS 1e-5f

constexpr int Bc = 32, Cc = 256, Hc = 56, Wc = 56;
constexpr int NHc = 8, HDc = 32, WSc = 7, SSc = 3;
constexpr int NTOK = 49;
constexpr int NWIN = 64;
constexpr int Lc = Hc * Wc;                 // 3136
constexpr int Mrows = Bc * NWIN * NTOK;     // 100352
constexpr int GIMG = 8;                     // images per group
constexpr int NGRP = Bc / GIMG;             // 4
constexpr int ROWS_G = GIMG * Lc;           // 25088
constexpr int WIN_G = GIMG * NWIN;          // 512

typedef short bf16x8 __attribute__((ext_vector_type(8)));
typedef float f32x4 __attribute__((ext_vector_type(4)));
typedef unsigned short u16x8 __attribute__((ext_vector_type(8)));

__device__ __forceinline__ float bf2f(unsigned short u) {
    return __uint_as_float(((unsigned)u) << 16);
}
__device__ __forceinline__ unsigned short f2bf(float f) {
    unsigned x = __float_as_uint(f);
    return (unsigned short)((x + 0x7fffu + ((x >> 16) & 1u)) >> 16);  // RNE
}

// ---------------------------------------------------------------- weight prep (fp32 -> bf16)
__global__ __launch_bounds__(256) void k_prep(const float* __restrict__ qkv_w,
                                              const float* __restrict__ proj_w,
                                              const float* __restrict__ w1,
                                              const float* __restrict__ w2,
                                              const float* __restrict__ qb,
                                              const float* __restrict__ vb,
                                              unsigned short* __restrict__ qkv_wb,
                                              unsigned short* __restrict__ proj_wb,
                                              unsigned short* __restrict__ w1b,
                                              unsigned short* __restrict__ w2b,
                                              float* __restrict__ qkvb) {
    int i = blockIdx.x * 256 + threadIdx.x;
    if (i < 768) qkvb[i] = (i < 256) ? qb[i] : ((i < 512) ? 0.f : vb[i - 512]);
    if (i < 196608) qkv_wb[i] = f2bf(qkv_w[i]);
    if (i < 65536)  proj_wb[i] = f2bf(proj_w[i]);
    if (i < 262144) { w1b[i] = f2bf(w1[i]); w2b[i] = f2bf(w2[i]); }
}

// ---------------------------------------------- LN1 + roll(-3,-3) + window partition -> bf16
__global__ __launch_bounds__(256) void k_ln1_part(const float* __restrict__ x,
                                                  const float* __restrict__ n1w,
                                                  const float* __restrict__ n1b,
                                                  unsigned short* __restrict__ xw) {
    __shared__ float s[Cc * 57];
    __shared__ float mu[Wc], rs[Wc];
    int b = blockIdx.x / Hc, h = blockIdx.x % Hc;
    int t = threadIdx.x;
    const float* xp = x + ((size_t)b * Cc) * Lc + h * Wc;
    for (int idx = t; idx < Cc * Wc; idx += 256) {
        int c = idx / Wc, w = idx % Wc;
        s[c * 57 + w] = xp[(size_t)c * Lc + w];
    }
    __syncthreads();
    int lane = t & 63, wv = t >> 6;
    for (int p = wv; p < Wc; p += 4) {
        float sum = 0.f, sq = 0.f;
        #pragma unroll
        for (int k = 0; k < 4; ++k) {
            float v = s[(lane + 64 * k) * 57 + p];
            sum += v; sq += v * v;
        }
        #pragma unroll
        for (int off = 32; off; off >>= 1) {
            sum += __shfl_xor(sum, off);
            sq  += __shfl_xor(sq, off);
        }
        if (lane == 0) {
            float m = sum / Cc;
            mu[p] = m;
            rs[p] = rsqrtf(sq / Cc - m * m + EPS);
        }
    }
    __syncthreads();
    float wc_ = n1w[t], bc_ = n1b[t];
    int hr = (h + Hc - SSc) % Hc;
    int whh = hr / WSc, th = hr % WSc;
    for (int p = 0; p < Wc; ++p) {
        int wr = (p + Wc - SSc) % Wc;
        int www = wr / WSc, tw = wr % WSc;
        int row = (b * NWIN + whh * 8 + www) * NTOK + th * WSc + tw;
        float v = (s[t * 57 + p] - mu[p]) * rs[p] * wc_ + bc_;
        xw[(size_t)row * Cc + t] = f2bf(v);
    }
}

// ---------------------------------------------- MFMA GEMM: out = A @ W^T + bias
// A (M,K) bf16 row-major, W (N,K) bf16 row-major, out fp32 or bf16.
// 128x128 tile, BK=32, 4 waves, each wave 64x64 (4x4 frags of 16x16x32).
template <bool OUT_BF16>
__global__ __launch_bounds__(256) void k_gemm_mfma(const unsigned short* __restrict__ A,
                                                   const unsigned short* __restrict__ W,
                                                   const float* __restrict__ bias,
                                                   void* __restrict__ outv,
                                                   int K, int Nd) {
    __shared__ unsigned short As[128 * 32];
    __shared__ unsigned short Bs[128 * 32];
    int t = threadIdx.x;
    int l = t & 63, w = t >> 6;
    int wm = w & 1, wn = w >> 1;
    int m0 = blockIdx.x * 128, n0 = blockIdx.y * 128;
    int lr = l & 15, lg = l >> 4;

    f32x4 acc[4][4];
    #pragma unroll
    for (int i = 0; i < 4; ++i)
        #pragma unroll
        for (int j = 0; j < 4; ++j)
            acc[i][j] = (f32x4){0.f, 0.f, 0.f, 0.f};

    for (int kt = 0; kt < K; kt += 32) {
        #pragma unroll
        for (int s = 0; s < 2; ++s) {
            int cid = t + s * 256;
            int row = cid >> 2, ch = cid & 3;
            u16x8 va = *(const u16x8*)(A + (size_t)(m0 + row) * K + kt + ch * 8);
            u16x8 vb = *(const u16x8*)(W + (size_t)(n0 + row) * K + kt + ch * 8);
            int off = (row * 32 + ch * 8) ^ ((row & 7) << 3);
            *(u16x8*)&As[off] = va;
            *(u16x8*)&Bs[off] = vb;
        }
        __syncthreads();
        bf16x8 af[4], bfr[4];
        #pragma unroll
        for (int i = 0; i < 4; ++i) {
            int ra = wm * 64 + i * 16 + lr;
            af[i] = *(bf16x8*)&As[(ra * 32 + lg * 8) ^ ((ra & 7) << 3)];
            int rb = wn * 64 + i * 16 + lr;
            bfr[i] = *(bf16x8*)&Bs[(rb * 32 + lg * 8) ^ ((rb & 7) << 3)];
        }
        #pragma unroll
        for (int i = 0; i < 4; ++i)
            #pragma unroll
            for (int j = 0; j < 4; ++j)
                acc[i][j] = __builtin_amdgcn_mfma_f32_16x16x32_bf16(af[i], bfr[j], acc[i][j], 0, 0, 0);
        __syncthreads();
    }

    float bj[4];
    #pragma unroll
    for (int j = 0; j < 4; ++j) bj[j] = bias[n0 + wn * 64 + j * 16 + lr];
    #pragma unroll
    for (int i = 0; i < 4; ++i) {
        #pragma unroll
        for (int j = 0; j < 4; ++j) {
            int col = n0 + wn * 64 + j * 16 + lr;
            #pragma unroll
            for (int r = 0; r < 4; ++r) {
                int row = m0 + wm * 64 + i * 16 + lg * 4 + r;
                float vv = acc[i][j][r] + bj[j];
                if (OUT_BF16)
                    ((unsigned short*)outv)[(size_t)row * Nd + col] = f2bf(vv);
                else
                    ((float*)outv)[(size_t)row * Nd + col] = vv;
            }
        }
    }
}

// ---------------------------------------------- window attention (bf16 qkv in, bf16 out)
__global__ __launch_bounds__(256) void k_attn(const unsigned short* __restrict__ qkv,
                                              const float* __restrict__ rpb,
                                              unsigned short* __restrict__ outb) {
    __shared__ float qs[NTOK * HDc];
    __shared__ float kt[HDc * NTOK];
    __shared__ float vs[NTOK * HDc];
    __shared__ float S[NTOK * NTOK];
    __shared__ int rid[NTOK];
    int bid = blockIdx.x;
    int b_ = bid >> 3, hh = bid & 7;
    int t = threadIdx.x;
    const float scale = 0.17677669529663687f;
    const unsigned short* base = qkv + (size_t)b_ * NTOK * 768 + hh * HDc;
    if (t < 196) {
        int n = t >> 2, dg = t & 3;
        const unsigned short* rp = base + n * 768 + dg * 8;
        u16x8 uq = *(const u16x8*)(rp);
        u16x8 uk = *(const u16x8*)(rp + 256);
        u16x8 uv = *(const u16x8*)(rp + 512);
        #pragma unroll
        for (int j = 0; j < 8; ++j) {
            int d = dg * 8 + j;
            qs[n * HDc + d] = bf2f(uq[j]) * scale;
            kt[d * NTOK + n] = bf2f(uk[j]);
            vs[n * HDc + d] = bf2f(uv[j]);
        }
    }
    if (t < NTOK) {
        int wi = b_ & 63;
        int wh = wi >> 3, ww = wi & 7;
        int gh = wh * 7 + t / 7, gw = ww * 7 + t % 7;
        int rh = gh < 49 ? 0 : (gh < 53 ? 1 : 2);
        int rw = gw < 49 ? 0 : (gw < 53 ? 1 : 2);
        rid[t] = rh * 3 + rw;
    }
    __syncthreads();
    for (int idx = t; idx < NTOK * NTOK; idx += 256) {
        int i = idx / NTOK, j = idx % NTOK;
        float dot = 0.f;
        #pragma unroll 8
        for (int d = 0; d < HDc; ++d)
            dot += qs[i * HDc + d] * kt[d * NTOK + j];
        int ih = i / 7, iw = i % 7, jh = j / 7, jw = j % 7;
        int rpi = (ih - jh + 6) * 13 + (iw - jw + 6);
        float bv = rpb[rpi * NHc + hh];
        float m = (rid[i] == rid[j]) ? 0.f : -100.f;
        S[idx] = dot + bv + m;
    }
    __syncthreads();
    int lane = t & 63, wv = t >> 6;
    for (int r = wv; r < NTOK; r += 4) {
        float v = (lane < NTOK) ? S[r * NTOK + lane] : -1e30f;
        float mx = v;
        #pragma unroll
        for (int off = 32; off; off >>= 1) mx = fmaxf(mx, __shfl_xor(mx, off));
        float e = (lane < NTOK) ? __expf(v - mx) : 0.f;
        float sum = e;
        #pragma unroll
        for (int off = 32; off; off >>= 1) sum += __shfl_xor(sum, off);
        if (lane < NTOK) S[r * NTOK + lane] = e / sum;
    }
    __syncthreads();
    for (int idx = t; idx < NTOK * HDc; idx += 256) {
        int i = idx >> 5, d = idx & 31;
        float acc = 0.f;
        #pragma unroll 7
        for (int j = 0; j < NTOK; ++j)
            acc += S[i * NTOK + j] * vs[j * HDc + d];
        outb[((size_t)b_ * NTOK + i) * Cc + hh * HDc + d] = f2bf(acc);
    }
}

// ---------------------------------------------- window-reverse + unshift + residual -> bf16 xs
__global__ __launch_bounds__(256) void k_scatter(const float* __restrict__ x,
                                                 const float* __restrict__ pj,
                                                 unsigned short* __restrict__ xs,
                                                 int b0) {
    __shared__ float s[Cc * 57];
    int bg = blockIdx.x / Hc, h = blockIdx.x % Hc;
    int b = b0 + bg;
    int t = threadIdx.x;
    const float* xp = x + ((size_t)b * Cc) * Lc + h * Wc;
    for (int idx = t; idx < Cc * Wc; idx += 256) {
        int c = idx / Wc, w = idx % Wc;
        s[c * 57 + w] = xp[(size_t)c * Lc + w];
    }
    __syncthreads();
    int hr = (h + Hc - SSc) % Hc;
    int whh = hr / WSc, th = hr % WSc;
    for (int p = 0; p < Wc; ++p) {
        int wr = (p + Wc - SSc) % Wc;
        int row = (bg * NWIN + whh * 8 + wr / WSc) * NTOK + th * WSc + (wr % WSc);
        xs[((size_t)b * Lc + h * Wc + p) * Cc + t] =
            f2bf(s[t * 57 + p] + pj[(size_t)row * Cc + t]);
    }
}

// ---------------------------------------------- fused LN2 + MLP (MFMA) + residual + NCHW out
// 32 rows/block, 256 threads (4 waves). hid kept in LDS (64KB, swizzled).
__global__ __launch_bounds__(256) void k_mlp_fused(const unsigned short* __restrict__ xs,
                                                   const float* __restrict__ n2w,
                                                   const float* __restrict__ n2b,
                                                   const unsigned short* __restrict__ w1b,
                                                   const float* __restrict__ b1,
                                                   const unsigned short* __restrict__ w2b,
                                                   const float* __restrict__ b2,
                                                   float* __restrict__ out) {
    __shared__ unsigned short xn[32 * 256];    // swizzled bf16, LN2 output
    __shared__ unsigned short hid[32 * 1024];  // swizzled bf16, fc1 output
    int t = threadIdx.x;
    int l = t & 63, w = t >> 6;
    int lr = l & 15, lg = l >> 4;
    int m0 = blockIdx.x * 32;

    // ---- Phase A: load xs rows, LN2, write normalized bf16 (swizzled)
    {
        int r = t >> 3, c0 = (t & 7) * 32;
        const unsigned short* xrow = xs + (size_t)(m0 + r) * Cc + c0;
        float v[32];
        float sum = 0.f, sq = 0.f;
        #pragma unroll
        for (int q = 0; q < 4; ++q) {
            u16x8 u = *(const u16x8*)(xrow + q * 8);
            #pragma unroll
            for (int j = 0; j < 8; ++j) {
                float f = bf2f(u[j]);
                v[q * 8 + j] = f;
                sum += f; sq += f * f;
            }
        }
        #pragma unroll
        for (int off = 1; off < 8; off <<= 1) {
            sum += __shfl_xor(sum, off);
            sq  += __shfl_xor(sq, off);
        }
        float mu = sum / Cc;
        float rsg = rsqrtf(sq / Cc - mu * mu + EPS);
        #pragma unroll
        for (int q = 0; q < 4; ++q) {
            u16x8 o;
            #pragma unroll
            for (int j = 0; j < 8; ++j) {
                int c = c0 + q * 8 + j;
                o[j] = f2bf((v[q * 8 + j] - mu) * rsg * n2w[c] + n2b[c]);
            }
            *(u16x8*)&xn[(r * 256 + c0 + q * 8) ^ ((r & 7) << 3)] = o;
        }
    }
    __syncthreads();

    // ---- Phase B: fc1 (N=1024, K=256). wave w owns n in [256w, 256w+256).
    {
        f32x4 acc1[2][16];
        #pragma unroll
        for (int mf = 0; mf < 2; ++mf)
            #pragma unroll
            for (int nf = 0; nf < 16; ++nf)
                acc1[mf][nf] = (f32x4){0.f, 0.f, 0.f, 0.f};
        for (int ks = 0; ks < 8; ++ks) {
            int k0 = ks * 32;
            bf16x8 a[2];
            #pragma unroll
            for (int mf = 0; mf < 2; ++mf) {
                int ra = mf * 16 + lr;
                a[mf] = *(bf16x8*)&xn[(ra * 256 + k0 + lg * 8) ^ ((ra & 7) << 3)];
            }
            #pragma unroll
            for (int nf = 0; nf < 16; ++nf) {
                int n = w * 256 + nf * 16 + lr;
                bf16x8 bfr = *(const bf16x8*)&w1b[(size_t)n * 256 + k0 + lg * 8];
                acc1[0][nf] = __builtin_amdgcn_mfma_f32_16x16x32_bf16(a[0], bfr, acc1[0][nf], 0, 0, 0);
                acc1[1][nf] = __builtin_amdgcn_mfma_f32_16x16x32_bf16(a[1], bfr, acc1[1][nf], 0, 0, 0);
            }
        }
        #pragma unroll
        for (int nf = 0; nf < 16; ++nf) {
            int n = w * 256 + nf * 16 + lr;
            float b1n = b1[n];
            #pragma unroll
            for (int mf = 0; mf < 2; ++mf) {
                #pragma unroll
                for (int r = 0; r < 4; ++r) {
                    int rw = mf * 16 + lg * 4 + r;
                    float vv = fmaxf(acc1[mf][nf][r] + b1n, 0.f);
                    hid[(rw * 1024 + n) ^ ((rw & 7) << 3)] = f2bf(vv);
                }
            }
        }
    }
    __syncthreads();

    // ---- Phase C: fc2 (N=256, K=1024). wave w owns n in [64w, 64w+64).
    {
        f32x4 acc2[2][4];
        #pragma unroll
        for (int mf = 0; mf < 2; ++mf)
            #pragma unroll
            for (int nf = 0; nf < 4; ++nf)
                acc2[mf][nf] = (f32x4){0.f, 0.f, 0.f, 0.f};
        for (int ks = 0; ks < 32; ++ks) {
            int k0 = ks * 32;
            bf16x8 a[2];
            #pragma unroll
            for (int mf = 0; mf < 2; ++mf) {
                int ra = mf * 16 + lr;
                a[mf] = *(bf16x8*)&hid[(ra * 1024 + k0 + lg * 8) ^ ((ra & 7) << 3)];
            }
            #pragma unroll
            for (int nf = 0; nf < 4; ++nf) {
                int n = w * 64 + nf * 16 + lr;
                bf16x8 bfr = *(const bf16x8*)&w2b[(size_t)n * 1024 + k0 + lg * 8];
                acc2[0][nf] = __builtin_amdgcn_mfma_f32_16x16x32_bf16(a[0], bfr, acc2[0][nf], 0, 0, 0);
                acc2[1][nf] = __builtin_amdgcn_mfma_f32_16x16x32_bf16(a[1], bfr, acc2[1][nf], 0, 0, 0);
            }
        }
        // epilogue: + b2 + residual(xs), NCHW store
        int b = m0 / Lc, l0 = m0 % Lc;
        #pragma unroll
        for (int nf = 0; nf < 4; ++nf) {
            int c = w * 64 + nf * 16 + lr;
            float b2c = b2[c];
            #pragma unroll
            for (int mf = 0; mf < 2; ++mf) {
                #pragma unroll
                for (int r = 0; r < 4; ++r) {
                    int rw = mf * 16 + lg * 4 + r;
                    float res = bf2f(xs[(size_t)(m0 + rw) * Cc + c]);
                    float vv = acc2[mf][nf][r] + b2c + res;
                    out[((size_t)b * Cc + c) * Lc + l0 + rw] = vv;
                }
            }
        }
    }
}

// ----------------------------------------------------------------- launch
extern "C" void kernel_launch(void* const* d_in, const int* in_sizes, int n_in,
                              void* d_out, int out_size, void* d_ws, size_t ws_size,
                              hipStream_t stream) {
    const float* x      = (const float*)d_in[0];
    const float* qkv_w  = (const float*)d_in[1];
    const float* q_bias = (const float*)d_in[2];
    const float* v_bias = (const float*)d_in[3];
    const float* proj_w = (const float*)d_in[4];
    const float* proj_b = (const float*)d_in[5];
    const float* rpb    = (const float*)d_in[6];
    const float* n1w    = (const float*)d_in[7];
    const float* n1b    = (const float*)d_in[8];
    const float* n2w    = (const float*)d_in[9];
    const float* n2b    = (const float*)d_in[10];
    const float* w1     = (const float*)d_in[11];
    const float* b1     = (const float*)d_in[12];
    const float* w2     = (const float*)d_in[13];
    const float* b2     = (const float*)d_in[14];

    // ws layout (all 64B-aligned): xs/xw bf16 51.38MB | qkvb 3KB | bf16 weights 1.54MB
    char* ws = (char*)d_ws;
    const size_t SZ_BF16 = (size_t)Mrows * Cc * 2;        // 51,380,224
    unsigned short* xw      = (unsigned short*)ws;
    float*          qkvb    = (float*)(ws + SZ_BF16);
    unsigned short* qkv_wb  = (unsigned short*)(ws + SZ_BF16 + 3072);
    unsigned short* proj_wb = qkv_wb + 196608;
    unsigned short* w1b     = proj_wb + 65536;
    unsigned short* w2b     = w1b + 262144;               // ends ~52.96MB

    // d_out as per-group scratch (fully overwritten by k_mlp_fused at the end):
    //   [0, 38.54MB)      qkv_g bf16 (25088 x 768)
    //   [38.54, 51.38MB)  attn_g bf16 (25088 x 256)
    //   [51.38, 77.07MB)  proj_g fp32 (25088 x 256)
    unsigned short* qkv_s  = (unsigned short*)d_out;
    unsigned short* attn_s = qkv_s + (size_t)ROWS_G * 768;
    float*          proj_s = (float*)(attn_s + (size_t)ROWS_G * Cc);

    k_prep<<<1024, 256, 0, stream>>>(qkv_w, proj_w, w1, w2, q_bias, v_bias,
                                     qkv_wb, proj_wb, w1b, w2b, qkvb);
    k_ln1_part<<<Bc * Hc, 256, 0, stream>>>(x, n1w, n1b, xw);

    for (int g = 0; g < NGRP; ++g) {
        const unsigned short* xw_g = xw + (size_t)g * ROWS_G * Cc;
        k_gemm_mfma<true><<<dim3(ROWS_G / 128, 768 / 128), 256, 0, stream>>>(
            xw_g, qkv_wb, qkvb, qkv_s, 256, 768);
        k_attn<<<WIN_G * NHc, 256, 0, stream>>>(qkv_s, rpb, attn_s);
        k_gemm_mfma<false><<<dim3(ROWS_G / 128, 256 / 128), 256, 0, stream>>>(
            attn_s, proj_wb, proj_b, proj_s, 256, 256);
        k_scatter<<<GIMG * Hc, 256, 0, stream>>>(x, proj_s, xw, g * GIMG);
    }

    k_mlp_fused<<<Mrows / 32, 256, 0, stream>>>(xw, n2w, n2b, w1b, b1, w2b, b2,
                                                (float*)d_out);
}

// Round 4
// 1005.675 us; speedup vs baseline: 6.0210x; 1.1757x over previous
//
#include <hip/hip_runtime.h>
#include <math.h>

#define EPS 1e-5f

constexpr int Bc = 32, Cc = 256, Hc = 56, Wc = 56;
constexpr int NHc = 8, HDc = 32, WSc = 7, SSc = 3;
constexpr int NTOK = 49;
constexpr int NWIN = 64;
constexpr int Lc = Hc * Wc;                 // 3136
constexpr int Mrows = Bc * NWIN * NTOK;     // 100352
constexpr int GIMG = 8;                     // images per group
constexpr int NGRP = Bc / GIMG;             // 4
constexpr int ROWS_G = GIMG * Lc;           // 25088
constexpr int WIN_G = GIMG * NWIN;          // 512

typedef short bf16x8 __attribute__((ext_vector_type(8)));
typedef float f32x4 __attribute__((ext_vector_type(4)));
typedef unsigned short u16x8 __attribute__((ext_vector_type(8)));

__device__ __forceinline__ float bf2f(unsigned short u) {
    return __uint_as_float(((unsigned)u) << 16);
}
__device__ __forceinline__ unsigned short f2bf(float f) {
    unsigned x = __float_as_uint(f);
    return (unsigned short)((x + 0x7fffu + ((x >> 16) & 1u)) >> 16);  // RNE
}

// ------------------------------------------------ weight prep
// qkv_w/proj_w -> plain bf16 rows; w1/w2 -> MFMA-frag-packed bf16:
//   packed[((n>>4)*(K>>3) + (k>>3))*128 + (n&15)*8 + (k&7)]
// so a B-fragment (n-tile 16, k-tile 32) is one contiguous 1KB wave load.
__global__ __launch_bounds__(256) void k_prep(const float* __restrict__ qkv_w,
                                              const float* __restrict__ proj_w,
                                              const float* __restrict__ w1,
                                              const float* __restrict__ w2,
                                              const float* __restrict__ qb,
                                              const float* __restrict__ vb,
                                              unsigned short* __restrict__ qkv_wb,
                                              unsigned short* __restrict__ proj_wb,
                                              unsigned short* __restrict__ w1t,
                                              unsigned short* __restrict__ w2t,
                                              float* __restrict__ qkvb) {
    int i = blockIdx.x * 256 + threadIdx.x;
    if (i < 768) qkvb[i] = (i < 256) ? qb[i] : ((i < 512) ? 0.f : vb[i - 512]);
    if (i < 196608) qkv_wb[i] = f2bf(qkv_w[i]);
    if (i < 65536)  proj_wb[i] = f2bf(proj_w[i]);
    if (i < 262144) {
        int n1 = i >> 8, k1 = i & 255;       // w1: (1024, 256)
        w1t[((n1 >> 4) * 32 + (k1 >> 3)) * 128 + (n1 & 15) * 8 + (k1 & 7)] = f2bf(w1[i]);
        int n2 = i >> 10, k2 = i & 1023;     // w2: (256, 1024)
        w2t[((n2 >> 4) * 128 + (k2 >> 3)) * 128 + (n2 & 15) * 8 + (k2 & 7)] = f2bf(w2[i]);
    }
}

// ------------------------------------------------ LN1 + roll + window partition (per group)
// Also stashes raw x as bf16 in (b_local, l, c) layout for the residual.
__global__ __launch_bounds__(256) void k_ln1_part(const float* __restrict__ x,
                                                  const float* __restrict__ n1w,
                                                  const float* __restrict__ n1b,
                                                  unsigned short* __restrict__ xw,
                                                  unsigned short* __restrict__ xres,
                                                  int b0) {
    __shared__ float s[Cc * 57];
    __shared__ float mu[Wc], rs[Wc];
    int bg = blockIdx.x / Hc, h = blockIdx.x % Hc;
    int b = b0 + bg;
    int t = threadIdx.x;
    const float* xp = x + ((size_t)b * Cc) * Lc + h * Wc;
    for (int idx = t; idx < Cc * Wc; idx += 256) {
        int c = idx / Wc, w = idx % Wc;
        s[c * 57 + w] = xp[(size_t)c * Lc + w];
    }
    __syncthreads();
    int lane = t & 63, wv = t >> 6;
    for (int p = wv; p < Wc; p += 4) {
        float sum = 0.f, sq = 0.f;
        #pragma unroll
        for (int k = 0; k < 4; ++k) {
            float v = s[(lane + 64 * k) * 57 + p];
            sum += v; sq += v * v;
        }
        #pragma unroll
        for (int off = 32; off; off >>= 1) {
            sum += __shfl_xor(sum, off);
            sq  += __shfl_xor(sq, off);
        }
        if (lane == 0) {
            float m = sum / Cc;
            mu[p] = m;
            rs[p] = rsqrtf(sq / Cc - m * m + EPS);
        }
    }
    __syncthreads();
    float wc_ = n1w[t], bc_ = n1b[t];
    int hr = (h + Hc - SSc) % Hc;
    int whh = hr / WSc, th = hr % WSc;
    for (int p = 0; p < Wc; ++p) {
        float raw = s[t * 57 + p];
        xres[((size_t)bg * Lc + h * Wc + p) * Cc + t] = f2bf(raw);
        int wr = (p + Wc - SSc) % Wc;
        int www = wr / WSc, tw = wr % WSc;
        int row = (b * NWIN + whh * 8 + www) * NTOK + th * WSc + tw;
        float v = (raw - mu[p]) * rs[p] * wc_ + bc_;
        xw[(size_t)row * Cc + t] = f2bf(v);
    }
}

// ------------------------------------------------ MFMA GEMM (qkv): out = A @ W^T + bias -> bf16
__global__ __launch_bounds__(256) void k_gemm_mfma(const unsigned short* __restrict__ A,
                                                   const unsigned short* __restrict__ W,
                                                   const float* __restrict__ bias,
                                                   unsigned short* __restrict__ outb,
                                                   int K, int Nd) {
    __shared__ unsigned short As[128 * 32];
    __shared__ unsigned short Bs[128 * 32];
    int t = threadIdx.x;
    int l = t & 63, w = t >> 6;
    int wm = w & 1, wn = w >> 1;
    int m0 = blockIdx.x * 128, n0 = blockIdx.y * 128;
    int lr = l & 15, lg = l >> 4;

    f32x4 acc[4][4];
    #pragma unroll
    for (int i = 0; i < 4; ++i)
        #pragma unroll
        for (int j = 0; j < 4; ++j)
            acc[i][j] = (f32x4){0.f, 0.f, 0.f, 0.f};

    for (int kt = 0; kt < K; kt += 32) {
        #pragma unroll
        for (int s = 0; s < 2; ++s) {
            int cid = t + s * 256;
            int row = cid >> 2, ch = cid & 3;
            u16x8 va = *(const u16x8*)(A + (size_t)(m0 + row) * K + kt + ch * 8);
            u16x8 vb = *(const u16x8*)(W + (size_t)(n0 + row) * K + kt + ch * 8);
            int off = (row * 32 + ch * 8) ^ ((row & 7) << 3);
            *(u16x8*)&As[off] = va;
            *(u16x8*)&Bs[off] = vb;
        }
        __syncthreads();
        bf16x8 af[4], bfr[4];
        #pragma unroll
        for (int i = 0; i < 4; ++i) {
            int ra = wm * 64 + i * 16 + lr;
            af[i] = *(bf16x8*)&As[(ra * 32 + lg * 8) ^ ((ra & 7) << 3)];
            int rb = wn * 64 + i * 16 + lr;
            bfr[i] = *(bf16x8*)&Bs[(rb * 32 + lg * 8) ^ ((rb & 7) << 3)];
        }
        #pragma unroll
        for (int i = 0; i < 4; ++i)
            #pragma unroll
            for (int j = 0; j < 4; ++j)
                acc[i][j] = __builtin_amdgcn_mfma_f32_16x16x32_bf16(af[i], bfr[j], acc[i][j], 0, 0, 0);
        __syncthreads();
    }

    float bj[4];
    #pragma unroll
    for (int j = 0; j < 4; ++j) bj[j] = bias[n0 + wn * 64 + j * 16 + lr];
    #pragma unroll
    for (int i = 0; i < 4; ++i)
        #pragma unroll
        for (int j = 0; j < 4; ++j) {
            int col = n0 + wn * 64 + j * 16 + lr;
            #pragma unroll
            for (int r = 0; r < 4; ++r) {
                int row = m0 + wm * 64 + i * 16 + lg * 4 + r;
                outb[(size_t)row * Nd + col] = f2bf(acc[i][j][r] + bj[j]);
            }
        }
}

// ------------------------------------------------ proj GEMM + fused window-reverse/unshift/residual
// A = attn_s (ROWS_G, 256) bf16, W = proj_wb (256,256) bf16.
// xs_g[(bg*L + l)*C + c] = bf16( xres_g + A@W^T + proj_b )
__global__ __launch_bounds__(256) void k_gemm_proj(const unsigned short* __restrict__ A,
                                                   const unsigned short* __restrict__ W,
                                                   const float* __restrict__ bias,
                                                   const unsigned short* __restrict__ xres,
                                                   unsigned short* __restrict__ xs) {
    __shared__ unsigned short As[128 * 32];
    __shared__ unsigned short Bs[128 * 32];
    constexpr int K = 256, Nd = 256;
    int t = threadIdx.x;
    int l = t & 63, w = t >> 6;
    int wm = w & 1, wn = w >> 1;
    int m0 = blockIdx.x * 128, n0 = blockIdx.y * 128;
    int lr = l & 15, lg = l >> 4;

    f32x4 acc[4][4];
    #pragma unroll
    for (int i = 0; i < 4; ++i)
        #pragma unroll
        for (int j = 0; j < 4; ++j)
            acc[i][j] = (f32x4){0.f, 0.f, 0.f, 0.f};

    for (int kt = 0; kt < K; kt += 32) {
        #pragma unroll
        for (int s = 0; s < 2; ++s) {
            int cid = t + s * 256;
            int row = cid >> 2, ch = cid & 3;
            u16x8 va = *(const u16x8*)(A + (size_t)(m0 + row) * K + kt + ch * 8);
            u16x8 vb = *(const u16x8*)(W + (size_t)(n0 + row) * K + kt + ch * 8);
            int off = (row * 32 + ch * 8) ^ ((row & 7) << 3);
            *(u16x8*)&As[off] = va;
            *(u16x8*)&Bs[off] = vb;
        }
        __syncthreads();
        bf16x8 af[4], bfr[4];
        #pragma unroll
        for (int i = 0; i < 4; ++i) {
            int ra = wm * 64 + i * 16 + lr;
            af[i] = *(bf16x8*)&As[(ra * 32 + lg * 8) ^ ((ra & 7) << 3)];
            int rb = wn * 64 + i * 16 + lr;
            bfr[i] = *(bf16x8*)&Bs[(rb * 32 + lg * 8) ^ ((rb & 7) << 3)];
        }
        #pragma unroll
        for (int i = 0; i < 4; ++i)
            #pragma unroll
            for (int j = 0; j < 4; ++j)
                acc[i][j] = __builtin_amdgcn_mfma_f32_16x16x32_bf16(af[i], bfr[j], acc[i][j], 0, 0, 0);
        __syncthreads();
    }

    float bj[4];
    #pragma unroll
    for (int j = 0; j < 4; ++j) bj[j] = bias[n0 + wn * 64 + j * 16 + lr];
    #pragma unroll
    for (int i = 0; i < 4; ++i)
        #pragma unroll
        for (int j = 0; j < 4; ++j) {
            int col = n0 + wn * 64 + j * 16 + lr;
            #pragma unroll
            for (int r = 0; r < 4; ++r) {
                int row = m0 + wm * 64 + i * 16 + lg * 4 + r;   // group-local window row
                int wl = row / NTOK, tok = row - wl * NTOK;
                int bg = wl >> 6, wi = wl & 63;
                int hr = (wi >> 3) * 7 + tok / 7;
                int wr = (wi & 7) * 7 + tok % 7;
                int hh = hr + SSc; if (hh >= Hc) hh -= Hc;
                int ww = wr + SSc; if (ww >= Wc) ww -= Wc;
                size_t didx = ((size_t)bg * Lc + hh * Wc + ww) * Cc + col;
                float res = bf2f(xres[didx]);
                xs[didx] = f2bf(res + acc[i][j][r] + bj[j]);
            }
        }
}

// ------------------------------------------------ window attention (bf16 in/out)
__global__ __launch_bounds__(256) void k_attn(const unsigned short* __restrict__ qkv,
                                              const float* __restrict__ rpb,
                                              unsigned short* __restrict__ outb) {
    __shared__ float qs[NTOK * HDc];
    __shared__ float kt[HDc * NTOK];
    __shared__ float vs[NTOK * HDc];
    __shared__ float S[NTOK * NTOK];
    __shared__ int rid[NTOK];
    int bid = blockIdx.x;
    int b_ = bid >> 3, hh = bid & 7;
    int t = threadIdx.x;
    const float scale = 0.17677669529663687f;
    const unsigned short* base = qkv + (size_t)b_ * NTOK * 768 + hh * HDc;
    if (t < 196) {
        int n = t >> 2, dg = t & 3;
        const unsigned short* rp = base + n * 768 + dg * 8;
        u16x8 uq = *(const u16x8*)(rp);
        u16x8 uk = *(const u16x8*)(rp + 256);
        u16x8 uv = *(const u16x8*)(rp + 512);
        #pragma unroll
        for (int j = 0; j < 8; ++j) {
            int d = dg * 8 + j;
            qs[n * HDc + d] = bf2f(uq[j]) * scale;
            kt[d * NTOK + n] = bf2f(uk[j]);
            vs[n * HDc + d] = bf2f(uv[j]);
        }
    }
    if (t < NTOK) {
        int wi = b_ & 63;
        int wh = wi >> 3, ww = wi & 7;
        int gh = wh * 7 + t / 7, gw = ww * 7 + t % 7;
        int rh = gh < 49 ? 0 : (gh < 53 ? 1 : 2);
        int rw = gw < 49 ? 0 : (gw < 53 ? 1 : 2);
        rid[t] = rh * 3 + rw;
    }
    __syncthreads();
    for (int idx = t; idx < NTOK * NTOK; idx += 256) {
        int i = idx / NTOK, j = idx % NTOK;
        float dot = 0.f;
        #pragma unroll 8
        for (int d = 0; d < HDc; ++d)
            dot += qs[i * HDc + d] * kt[d * NTOK + j];
        int ih = i / 7, iw = i % 7, jh = j / 7, jw = j % 7;
        int rpi = (ih - jh + 6) * 13 + (iw - jw + 6);
        float bv = rpb[rpi * NHc + hh];
        float m = (rid[i] == rid[j]) ? 0.f : -100.f;
        S[idx] = dot + bv + m;
    }
    __syncthreads();
    int lane = t & 63, wv = t >> 6;
    for (int r = wv; r < NTOK; r += 4) {
        float v = (lane < NTOK) ? S[r * NTOK + lane] : -1e30f;
        float mx = v;
        #pragma unroll
        for (int off = 32; off; off >>= 1) mx = fmaxf(mx, __shfl_xor(mx, off));
        float e = (lane < NTOK) ? __expf(v - mx) : 0.f;
        float sum = e;
        #pragma unroll
        for (int off = 32; off; off >>= 1) sum += __shfl_xor(sum, off);
        if (lane < NTOK) S[r * NTOK + lane] = e / sum;
    }
    __syncthreads();
    for (int idx = t; idx < NTOK * HDc; idx += 256) {
        int i = idx >> 5, d = idx & 31;
        float acc = 0.f;
        #pragma unroll 7
        for (int j = 0; j < NTOK; ++j)
            acc += S[i * NTOK + j] * vs[j * HDc + d];
        outb[((size_t)b_ * NTOK + i) * Cc + hh * HDc + d] = f2bf(acc);
    }
}

// ------------------------------------------------ fused LN2 + MLP + residual + NCHW out
// 64 rows/block, 512 threads (2x4 waves). Hidden processed in 8 chunks of 128
// staged in LDS; fc2 accumulators live in registers across chunks.
#define XNI(r, c)  (((r) * 256 + (c)) ^ (((r) & 7) << 3))
#define HIDI(r, c) (((r) * 128 + (c)) ^ (((r) & 7) << 3))
__global__ __launch_bounds__(512) void k_mlp_fused(const unsigned short* __restrict__ xs,
                                                   const float* __restrict__ n2w,
                                                   const float* __restrict__ n2b,
                                                   const unsigned short* __restrict__ w1t,
                                                   const float* __restrict__ b1,
                                                   const unsigned short* __restrict__ w2t,
                                                   const float* __restrict__ b2,
                                                   float* __restrict__ out) {
    __shared__ unsigned short xn[64 * 256];    // LN2 output, swizzled bf16
    __shared__ unsigned short hid[64 * 128];   // hidden chunk, swizzled bf16
    int t = threadIdx.x;
    int l = t & 63, w = t >> 6;
    int wn = w & 3, wm = w >> 2;
    int lr = l & 15, lg = l >> 4;
    int m0 = blockIdx.x * 64;

    // Phase A: LN2 (8 lanes per row)
    {
        int r = t >> 3, c0 = (t & 7) * 32;
        const unsigned short* xrow = xs + (size_t)(m0 + r) * Cc + c0;
        float v[32];
        float sum = 0.f, sq = 0.f;
        #pragma unroll
        for (int q = 0; q < 4; ++q) {
            u16x8 u = *(const u16x8*)(xrow + q * 8);
            #pragma unroll
            for (int j = 0; j < 8; ++j) {
                float f = bf2f(u[j]);
                v[q * 8 + j] = f;
                sum += f; sq += f * f;
            }
        }
        #pragma unroll
        for (int off = 1; off < 8; off <<= 1) {
            sum += __shfl_xor(sum, off);
            sq  += __shfl_xor(sq, off);
        }
        float mu = sum / Cc;
        float rsg = rsqrtf(sq / Cc - mu * mu + EPS);
        #pragma unroll
        for (int q = 0; q < 4; ++q) {
            u16x8 o;
            #pragma unroll
            for (int j = 0; j < 8; ++j) {
                int c = c0 + q * 8 + j;
                o[j] = f2bf((v[q * 8 + j] - mu) * rsg * n2w[c] + n2b[c]);
            }
            *(u16x8*)&xn[XNI(r, c0 + q * 8)] = o;
        }
    }
    __syncthreads();

    f32x4 acc2[2][4];
    #pragma unroll
    for (int mf = 0; mf < 2; ++mf)
        #pragma unroll
        for (int nf = 0; nf < 4; ++nf)
            acc2[mf][nf] = (f32x4){0.f, 0.f, 0.f, 0.f};

    for (int ch = 0; ch < 8; ++ch) {
        // fc1: hid chunk (64 x 128). wave (wm,wn): m in [wm*32, +32), h-local in [wn*32, +32)
        f32x4 acc1[2][2];
        #pragma unroll
        for (int mf = 0; mf < 2; ++mf)
            #pragma unroll
            for (int nf = 0; nf < 2; ++nf)
                acc1[mf][nf] = (f32x4){0.f, 0.f, 0.f, 0.f};
        #pragma unroll
        for (int ks = 0; ks < 8; ++ks) {
            bf16x8 a[2];
            #pragma unroll
            for (int mf = 0; mf < 2; ++mf) {
                int ra = wm * 32 + mf * 16 + lr;
                a[mf] = *(bf16x8*)&xn[XNI(ra, ks * 32 + lg * 8)];
            }
            #pragma unroll
            for (int nf = 0; nf < 2; ++nf) {
                int n0g = ch * 128 + wn * 32 + nf * 16;
                bf16x8 bfr = *(const bf16x8*)&w1t[((n0g >> 4) * 32 + ks * 4) * 128 + l * 8];
                acc1[0][nf] = __builtin_amdgcn_mfma_f32_16x16x32_bf16(a[0], bfr, acc1[0][nf], 0, 0, 0);
                acc1[1][nf] = __builtin_amdgcn_mfma_f32_16x16x32_bf16(a[1], bfr, acc1[1][nf], 0, 0, 0);
            }
        }
        __syncthreads();   // prior chunk's fc2 reads done before overwriting hid
        #pragma unroll
        for (int nf = 0; nf < 2; ++nf) {
            float b1n = b1[ch * 128 + wn * 32 + nf * 16 + lr];
            #pragma unroll
            for (int mf = 0; mf < 2; ++mf)
                #pragma unroll
                for (int r = 0; r < 4; ++r) {
                    int m = wm * 32 + mf * 16 + lg * 4 + r;
                    hid[HIDI(m, wn * 32 + nf * 16 + lr)] = f2bf(fmaxf(acc1[mf][nf][r] + b1n, 0.f));
                }
        }
        __syncthreads();
        // fc2 partial over this chunk's 128 h-dims. wave: m in [wm*32,+32), n in [wn*64,+64)
        #pragma unroll
        for (int ks = 0; ks < 4; ++ks) {
            bf16x8 a[2];
            #pragma unroll
            for (int mf = 0; mf < 2; ++mf) {
                int ra = wm * 32 + mf * 16 + lr;
                a[mf] = *(bf16x8*)&hid[HIDI(ra, ks * 32 + lg * 8)];
            }
            #pragma unroll
            for (int nf = 0; nf < 4; ++nf) {
                int n0g = wn * 64 + nf * 16;
                bf16x8 bfr = *(const bf16x8*)&w2t[((n0g >> 4) * 128 + ch * 16 + ks * 4) * 128 + l * 8];
                acc2[0][nf] = __builtin_amdgcn_mfma_f32_16x16x32_bf16(a[0], bfr, acc2[0][nf], 0, 0, 0);
                acc2[1][nf] = __builtin_amdgcn_mfma_f32_16x16x32_bf16(a[1], bfr, acc2[1][nf], 0, 0, 0);
            }
        }
    }

    // epilogue: + b2 + residual, NCHW store
    int b = m0 / Lc, l0 = m0 % Lc;
    #pragma unroll
    for (int nf = 0; nf < 4; ++nf) {
        int c = wn * 64 + nf * 16 + lr;
        float b2c = b2[c];
        #pragma unroll
        for (int mf = 0; mf < 2; ++mf)
            #pragma unroll
            for (int r = 0; r < 4; ++r) {
                int m = wm * 32 + mf * 16 + lg * 4 + r;
                float res = bf2f(xs[(size_t)(m0 + m) * Cc + c]);
                out[((size_t)b * Cc + c) * Lc + l0 + m] = acc2[mf][nf][r] + b2c + res;
            }
    }
}

// ----------------------------------------------------------------- launch
extern "C" void kernel_launch(void* const* d_in, const int* in_sizes, int n_in,
                              void* d_out, int out_size, void* d_ws, size_t ws_size,
                              hipStream_t stream) {
    const float* x      = (const float*)d_in[0];
    const float* qkv_w  = (const float*)d_in[1];
    const float* q_bias = (const float*)d_in[2];
    const float* v_bias = (const float*)d_in[3];
    const float* proj_w = (const float*)d_in[4];
    const float* proj_b = (const float*)d_in[5];
    const float* rpb    = (const float*)d_in[6];
    const float* n1w    = (const float*)d_in[7];
    const float* n1b    = (const float*)d_in[8];
    const float* n2w    = (const float*)d_in[9];
    const float* n2b    = (const float*)d_in[10];
    const float* w1     = (const float*)d_in[11];
    const float* b1     = (const float*)d_in[12];
    const float* w2     = (const float*)d_in[13];
    const float* b2     = (const float*)d_in[14];

    // ws: xw/xs bf16 51.38MB | qkvb 3KB | qkv_wb 384KB | proj_wb 128KB | w1t 512KB | w2t 512KB
    char* ws = (char*)d_ws;
    const size_t SZ_BF16 = (size_t)Mrows * Cc * 2;
    unsigned short* xw      = (unsigned short*)ws;          // xw, later xs (b,l,c)
    float*          qkvb    = (float*)(ws + SZ_BF16);
    unsigned short* qkv_wb  = (unsigned short*)(ws + SZ_BF16 + 3072);
    unsigned short* proj_wb = qkv_wb + 196608;
    unsigned short* w1t     = proj_wb + 65536;
    unsigned short* w2t     = w1t + 262144;

    // d_out scratch (fully overwritten by k_mlp_fused):
    //   qkv_s  bf16 (25088 x 768)  38.5MB
    //   attn_s bf16 (25088 x 256)  12.8MB
    //   xres_g bf16 (25088 x 256)  12.8MB
    unsigned short* qkv_s  = (unsigned short*)d_out;
    unsigned short* attn_s = qkv_s + (size_t)ROWS_G * 768;
    unsigned short* xres_s = attn_s + (size_t)ROWS_G * Cc;

    k_prep<<<1024, 256, 0, stream>>>(qkv_w, proj_w, w1, w2, q_bias, v_bias,
                                     qkv_wb, proj_wb, w1t, w2t, qkvb);

    for (int g = 0; g < NGRP; ++g) {
        unsigned short* xw_g = xw + (size_t)g * ROWS_G * Cc;   // also xs_g (same rows)
        k_ln1_part<<<GIMG * Hc, 256, 0, stream>>>(x, n1w, n1b, xw, xres_s, g * GIMG);
        k_gemm_mfma<<<dim3(ROWS_G / 128, 768 / 128), 256, 0, stream>>>(
            xw_g, qkv_wb, qkvb, qkv_s, 256, 768);
        k_attn<<<WIN_G * NHc, 256, 0, stream>>>(qkv_s, rpb, attn_s);
        k_gemm_proj<<<dim3(ROWS_G / 128, 2), 256, 0, stream>>>(
            attn_s, proj_wb, proj_b, xres_s, xw_g);
    }

    k_mlp_fused<<<Mrows / 64, 512, 0, stream>>>(xw, n2w, n2b, w1t, b1, w2t, b2,
                                                (float*)d_out);
}

// Round 6
// 786.565 us; speedup vs baseline: 7.6983x; 1.2786x over previous
//
#include <hip/hip_runtime.h>
#include <math.h>

#define EPS 1e-5f

constexpr int Bc = 32, Cc = 256, Hc = 56, Wc = 56;
constexpr int NHc = 8, HDc = 32, WSc = 7, SSc = 3;
constexpr int NTOK = 49;
constexpr int NWIN = 64;
constexpr int Lc = Hc * Wc;                 // 3136
constexpr int Mrows = Bc * NWIN * NTOK;     // 100352
constexpr int GIMG = 8;                     // images per group
constexpr int NGRP = Bc / GIMG;             // 4
constexpr int ROWS_G = GIMG * Lc;           // 25088
constexpr int WIN_G = GIMG * NWIN;          // 512

typedef short bf16x8 __attribute__((ext_vector_type(8)));
typedef float f32x4 __attribute__((ext_vector_type(4)));
typedef unsigned short u16x8 __attribute__((ext_vector_type(8)));

__device__ __forceinline__ float bf2f(unsigned short u) {
    return __uint_as_float(((unsigned)u) << 16);
}
__device__ __forceinline__ unsigned short f2bf(float f) {
    unsigned x = __float_as_uint(f);
    return (unsigned short)((x + 0x7fffu + ((x >> 16) & 1u)) >> 16);  // RNE
}

// ------------------------------------------------ weight prep
// qkv_w/proj_w -> plain bf16 rows.
// w1 (1024,256) -> frag-packed, n-major: ((n>>4)*32+(k>>3))*128 + (n&15)*8 + (k&7)
//   => h-chunk of 64 n's = contiguous 32KB.
// w2 (256,1024) -> frag-packed, k-chunk-major:
//   ((k>>6)*32 + (n>>4)*2 + ((k>>5)&1))*512 + ((k>>3)&3)*128 + (n&15)*8 + (k&7)
//   => h-chunk of 64 k's (all 256 n) = contiguous 32KB.  [bijective: all k bits kept]
__global__ __launch_bounds__(256) void k_prep(const float* __restrict__ qkv_w,
                                              const float* __restrict__ proj_w,
                                              const float* __restrict__ w1,
                                              const float* __restrict__ w2,
                                              const float* __restrict__ qb,
                                              const float* __restrict__ vb,
                                              unsigned short* __restrict__ qkv_wb,
                                              unsigned short* __restrict__ proj_wb,
                                              unsigned short* __restrict__ w1t,
                                              unsigned short* __restrict__ w2t,
                                              float* __restrict__ qkvb) {
    int i = blockIdx.x * 256 + threadIdx.x;
    if (i < 768) qkvb[i] = (i < 256) ? qb[i] : ((i < 512) ? 0.f : vb[i - 512]);
    if (i < 196608) qkv_wb[i] = f2bf(qkv_w[i]);
    if (i < 65536)  proj_wb[i] = f2bf(proj_w[i]);
    if (i < 262144) {
        int n1 = i >> 8, k1 = i & 255;       // w1: (1024, 256)
        w1t[((n1 >> 4) * 32 + (k1 >> 3)) * 128 + (n1 & 15) * 8 + (k1 & 7)] = f2bf(w1[i]);
        int n2 = i >> 10, k2 = i & 1023;     // w2: (256, 1024)
        w2t[((k2 >> 6) * 32 + (n2 >> 4) * 2 + ((k2 >> 5) & 1)) * 512 +
            ((k2 >> 3) & 3) * 128 + (n2 & 15) * 8 + (k2 & 7)] = f2bf(w2[i]);
    }
}

// ------------------------------------------------ LN1 + roll + window partition (per group)
__global__ __launch_bounds__(256) void k_ln1_part(const float* __restrict__ x,
                                                  const float* __restrict__ n1w,
                                                  const float* __restrict__ n1b,
                                                  unsigned short* __restrict__ xw,
                                                  unsigned short* __restrict__ xres,
                                                  int b0) {
    __shared__ float s[Cc * 57];
    __shared__ float mu[Wc], rs[Wc];
    int bg = blockIdx.x / Hc, h = blockIdx.x % Hc;
    int b = b0 + bg;
    int t = threadIdx.x;
    const float* xp = x + ((size_t)b * Cc) * Lc + h * Wc;
    for (int idx = t; idx < Cc * Wc; idx += 256) {
        int c = idx / Wc, w = idx % Wc;
        s[c * 57 + w] = xp[(size_t)c * Lc + w];
    }
    __syncthreads();
    int lane = t & 63, wv = t >> 6;
    for (int p = wv; p < Wc; p += 4) {
        float sum = 0.f, sq = 0.f;
        #pragma unroll
        for (int k = 0; k < 4; ++k) {
            float v = s[(lane + 64 * k) * 57 + p];
            sum += v; sq += v * v;
        }
        #pragma unroll
        for (int off = 32; off; off >>= 1) {
            sum += __shfl_xor(sum, off);
            sq  += __shfl_xor(sq, off);
        }
        if (lane == 0) {
            float m = sum / Cc;
            mu[p] = m;
            rs[p] = rsqrtf(sq / Cc - m * m + EPS);
        }
    }
    __syncthreads();
    float wc_ = n1w[t], bc_ = n1b[t];
    int hr = (h + Hc - SSc) % Hc;
    int whh = hr / WSc, th = hr % WSc;
    for (int p = 0; p < Wc; ++p) {
        float raw = s[t * 57 + p];
        xres[((size_t)bg * Lc + h * Wc + p) * Cc + t] = f2bf(raw);
        int wr = (p + Wc - SSc) % Wc;
        int www = wr / WSc, tw = wr % WSc;
        int row = (b * NWIN + whh * 8 + www) * NTOK + th * WSc + tw;
        float v = (raw - mu[p]) * rs[p] * wc_ + bc_;
        xw[(size_t)row * Cc + t] = f2bf(v);
    }
}

// ------------------------------------------------ MFMA GEMM (qkv): out = A @ W^T + bias -> bf16
__global__ __launch_bounds__(256) void k_gemm_mfma(const unsigned short* __restrict__ A,
                                                   const unsigned short* __restrict__ W,
                                                   const float* __restrict__ bias,
                                                   unsigned short* __restrict__ outb,
                                                   int K, int Nd) {
    __shared__ unsigned short As[128 * 32];
    __shared__ unsigned short Bs[128 * 32];
    int t = threadIdx.x;
    int l = t & 63, w = t >> 6;
    int wm = w & 1, wn = w >> 1;
    int m0 = blockIdx.x * 128, n0 = blockIdx.y * 128;
    int lr = l & 15, lg = l >> 4;

    f32x4 acc[4][4];
    #pragma unroll
    for (int i = 0; i < 4; ++i)
        #pragma unroll
        for (int j = 0; j < 4; ++j)
            acc[i][j] = (f32x4){0.f, 0.f, 0.f, 0.f};

    for (int kt = 0; kt < K; kt += 32) {
        #pragma unroll
        for (int s = 0; s < 2; ++s) {
            int cid = t + s * 256;
            int row = cid >> 2, ch = cid & 3;
            u16x8 va = *(const u16x8*)(A + (size_t)(m0 + row) * K + kt + ch * 8);
            u16x8 vb = *(const u16x8*)(W + (size_t)(n0 + row) * K + kt + ch * 8);
            int off = (row * 32 + ch * 8) ^ ((row & 7) << 3);
            *(u16x8*)&As[off] = va;
            *(u16x8*)&Bs[off] = vb;
        }
        __syncthreads();
        bf16x8 af[4], bfr[4];
        #pragma unroll
        for (int i = 0; i < 4; ++i) {
            int ra = wm * 64 + i * 16 + lr;
            af[i] = *(bf16x8*)&As[(ra * 32 + lg * 8) ^ ((ra & 7) << 3)];
            int rb = wn * 64 + i * 16 + lr;
            bfr[i] = *(bf16x8*)&Bs[(rb * 32 + lg * 8) ^ ((rb & 7) << 3)];
        }
        #pragma unroll
        for (int i = 0; i < 4; ++i)
            #pragma unroll
            for (int j = 0; j < 4; ++j)
                acc[i][j] = __builtin_amdgcn_mfma_f32_16x16x32_bf16(af[i], bfr[j], acc[i][j], 0, 0, 0);
        __syncthreads();
    }

    float bj[4];
    #pragma unroll
    for (int j = 0; j < 4; ++j) bj[j] = bias[n0 + wn * 64 + j * 16 + lr];
    #pragma unroll
    for (int i = 0; i < 4; ++i)
        #pragma unroll
        for (int j = 0; j < 4; ++j) {
            int col = n0 + wn * 64 + j * 16 + lr;
            #pragma unroll
            for (int r = 0; r < 4; ++r) {
                int row = m0 + wm * 64 + i * 16 + lg * 4 + r;
                outb[(size_t)row * Nd + col] = f2bf(acc[i][j][r] + bj[j]);
            }
        }
}

// ------------------------------------------------ proj GEMM + fused window-reverse/unshift/residual
__global__ __launch_bounds__(256) void k_gemm_proj(const unsigned short* __restrict__ A,
                                                   const unsigned short* __restrict__ W,
                                                   const float* __restrict__ bias,
                                                   const unsigned short* __restrict__ xres,
                                                   unsigned short* __restrict__ xs) {
    __shared__ unsigned short As[128 * 32];
    __shared__ unsigned short Bs[128 * 32];
    constexpr int K = 256;
    int t = threadIdx.x;
    int l = t & 63, w = t >> 6;
    int wm = w & 1, wn = w >> 1;
    int m0 = blockIdx.x * 128, n0 = blockIdx.y * 128;
    int lr = l & 15, lg = l >> 4;

    f32x4 acc[4][4];
    #pragma unroll
    for (int i = 0; i < 4; ++i)
        #pragma unroll
        for (int j = 0; j < 4; ++j)
            acc[i][j] = (f32x4){0.f, 0.f, 0.f, 0.f};

    for (int kt = 0; kt < K; kt += 32) {
        #pragma unroll
        for (int s = 0; s < 2; ++s) {
            int cid = t + s * 256;
            int row = cid >> 2, ch = cid & 3;
            u16x8 va = *(const u16x8*)(A + (size_t)(m0 + row) * K + kt + ch * 8);
            u16x8 vb = *(const u16x8*)(W + (size_t)(n0 + row) * K + kt + ch * 8);
            int off = (row * 32 + ch * 8) ^ ((row & 7) << 3);
            *(u16x8*)&As[off] = va;
            *(u16x8*)&Bs[off] = vb;
        }
        __syncthreads();
        bf16x8 af[4], bfr[4];
        #pragma unroll
        for (int i = 0; i < 4; ++i) {
            int ra = wm * 64 + i * 16 + lr;
            af[i] = *(bf16x8*)&As[(ra * 32 + lg * 8) ^ ((ra & 7) << 3)];
            int rb = wn * 64 + i * 16 + lr;
            bfr[i] = *(bf16x8*)&Bs[(rb * 32 + lg * 8) ^ ((rb & 7) << 3)];
        }
        #pragma unroll
        for (int i = 0; i < 4; ++i)
            #pragma unroll
            for (int j = 0; j < 4; ++j)
                acc[i][j] = __builtin_amdgcn_mfma_f32_16x16x32_bf16(af[i], bfr[j], acc[i][j], 0, 0, 0);
        __syncthreads();
    }

    float bj[4];
    #pragma unroll
    for (int j = 0; j < 4; ++j) bj[j] = bias[n0 + wn * 64 + j * 16 + lr];
    #pragma unroll
    for (int i = 0; i < 4; ++i)
        #pragma unroll
        for (int j = 0; j < 4; ++j) {
            int col = n0 + wn * 64 + j * 16 + lr;
            #pragma unroll
            for (int r = 0; r < 4; ++r) {
                int row = m0 + wm * 64 + i * 16 + lg * 4 + r;   // group-local window row
                int wl = row / NTOK, tok = row - wl * NTOK;
                int bg = wl >> 6, wi = wl & 63;
                int hr = (wi >> 3) * 7 + tok / 7;
                int wr = (wi & 7) * 7 + tok % 7;
                int hh = hr + SSc; if (hh >= Hc) hh -= Hc;
                int ww = wr + SSc; if (ww >= Wc) ww -= Wc;
                size_t didx = ((size_t)bg * Lc + hh * Wc + ww) * Cc + col;
                float res = bf2f(xres[didx]);
                xs[didx] = f2bf(res + acc[i][j][r] + bj[j]);
            }
        }
}

// ------------------------------------------------ window attention v2 (vectorized, padded LDS)
__global__ __launch_bounds__(256) void k_attn(const unsigned short* __restrict__ qkv,
                                              const float* __restrict__ rpb,
                                              unsigned short* __restrict__ outb) {
    constexpr int PD = 36;   // padded row stride (floats)
    __shared__ float qs[NTOK * PD];
    __shared__ float ks_[NTOK * PD];
    __shared__ float vs[NTOK * PD];
    __shared__ float S[NTOK * NTOK];
    __shared__ int rid[NTOK];
    int bid = blockIdx.x;
    int b_ = bid >> 3, hh = bid & 7;
    int t = threadIdx.x;
    const float scale = 0.17677669529663687f;
    const unsigned short* base = qkv + (size_t)b_ * NTOK * 768 + hh * HDc;
    if (t < 196) {
        int n = t >> 2, dg = t & 3;
        const unsigned short* rp = base + n * 768 + dg * 8;
        u16x8 uq = *(const u16x8*)(rp);
        u16x8 uk = *(const u16x8*)(rp + 256);
        u16x8 uv = *(const u16x8*)(rp + 512);
        #pragma unroll
        for (int j = 0; j < 8; ++j) {
            int d = dg * 8 + j;
            qs[n * PD + d]  = bf2f(uq[j]) * scale;
            ks_[n * PD + d] = bf2f(uk[j]);
            vs[n * PD + d]  = bf2f(uv[j]);
        }
    }
    if (t < NTOK) {
        int wi = b_ & 63;
        int wh = wi >> 3, ww = wi & 7;
        int gh = wh * 7 + t / 7, gw = ww * 7 + t % 7;
        int rh = gh < 49 ? 0 : (gh < 53 ? 1 : 2);
        int rw = gw < 49 ? 0 : (gw < 53 ? 1 : 2);
        rid[t] = rh * 3 + rw;
    }
    __syncthreads();
    // S phase: 343 strips of (i, 7 j's), q-row cached in registers
    for (int item = t; item < 343; item += 256) {
        int i = item / 7, s = item % 7;
        float4 qr[8];
        #pragma unroll
        for (int dd = 0; dd < 8; ++dd) qr[dd] = *(const float4*)&qs[i * PD + dd * 4];
        int ih = i / 7, iw = i % 7;
        #pragma unroll
        for (int jj = 0; jj < 7; ++jj) {
            int j = s * 7 + jj;
            float dot = 0.f;
            #pragma unroll
            for (int dd = 0; dd < 8; ++dd) {
                float4 kr = *(const float4*)&ks_[j * PD + dd * 4];
                dot += qr[dd].x * kr.x + qr[dd].y * kr.y + qr[dd].z * kr.z + qr[dd].w * kr.w;
            }
            int jh = j / 7, jw = j % 7;
            int rpi = (ih - jh + 6) * 13 + (iw - jw + 6);
            float bv = rpb[rpi * NHc + hh];
            float m = (rid[i] == rid[j]) ? 0.f : -100.f;
            S[i * NTOK + j] = dot + bv + m;
        }
    }
    __syncthreads();
    int lane = t & 63, wv = t >> 6;
    for (int r = wv; r < NTOK; r += 4) {
        float v = (lane < NTOK) ? S[r * NTOK + lane] : -1e30f;
        float mx = v;
        #pragma unroll
        for (int off = 32; off; off >>= 1) mx = fmaxf(mx, __shfl_xor(mx, off));
        float e = (lane < NTOK) ? __expf(v - mx) : 0.f;
        float sum = e;
        #pragma unroll
        for (int off = 32; off; off >>= 1) sum += __shfl_xor(sum, off);
        if (lane < NTOK) S[r * NTOK + lane] = e / sum;
    }
    __syncthreads();
    // PV phase: thread owns (i, 8 d's)
    if (t < 196) {
        int i = t >> 2, d0 = (t & 3) * 8;
        float acc[8] = {};
        for (int j = 0; j < NTOK; ++j) {
            float p = S[i * NTOK + j];
            float4 v0 = *(const float4*)&vs[j * PD + d0];
            float4 v1 = *(const float4*)&vs[j * PD + d0 + 4];
            acc[0] += p * v0.x; acc[1] += p * v0.y; acc[2] += p * v0.z; acc[3] += p * v0.w;
            acc[4] += p * v1.x; acc[5] += p * v1.y; acc[6] += p * v1.z; acc[7] += p * v1.w;
        }
        u16x8 o;
        #pragma unroll
        for (int e = 0; e < 8; ++e) o[e] = f2bf(acc[e]);
        *(u16x8*)&outb[((size_t)b_ * NTOK + i) * Cc + hh * HDc + d0] = o;
    }
}

// ------------------------------------------------ fused LN2 + MLP v3 + residual + NCHW out
// 128 rows/block, 512 threads (8 waves: wm = w>>1 owns 32 rows, wn = w&1).
// xn A-frags in registers; weights streamed per 64-h chunk through LDS; hid 16KB swizzled.
#define HIDX(m, c) (((m) * 64 + (c)) ^ (((m) & 7) << 3))
__global__ __launch_bounds__(512) void k_mlp_fused(const unsigned short* __restrict__ xs,
                                                   const float* __restrict__ n2w,
                                                   const float* __restrict__ n2b,
                                                   const unsigned short* __restrict__ w1t,
                                                   const float* __restrict__ b1,
                                                   const unsigned short* __restrict__ w2t,
                                                   const float* __restrict__ b2,
                                                   float* __restrict__ out) {
    __shared__ unsigned short w1s[16384];   // 64n x 256k, frag-contig (32KB)
    __shared__ unsigned short w2s[16384];   // 256n x 64k, frag-contig (32KB)
    __shared__ unsigned short hid[8192];    // 128m x 64c, swizzled (16KB)
    int t = threadIdx.x;
    int l = t & 63, w = t >> 6;
    int wm = w >> 1, wn = w & 1;
    int lr = l & 15, lg = l >> 4;
    int m0 = blockIdx.x * 128;

    // ---- Phase A (registers only): load 2 rows/lane, LN2, build bf16 A-frags
    bf16x8 xf[2][8];
    {
        #pragma unroll
        for (int mf = 0; mf < 2; ++mf) {
            int row = m0 + wm * 32 + mf * 16 + lr;
            const unsigned short* xrow = xs + (size_t)row * Cc;
            u16x8 raw[8];
            float sum = 0.f, sq = 0.f;
            #pragma unroll
            for (int ks = 0; ks < 8; ++ks) {
                raw[ks] = *(const u16x8*)(xrow + ks * 32 + lg * 8);
                #pragma unroll
                for (int e = 0; e < 8; ++e) {
                    float f = bf2f(raw[ks][e]);
                    sum += f; sq += f * f;
                }
            }
            sum += __shfl_xor(sum, 16); sq += __shfl_xor(sq, 16);
            sum += __shfl_xor(sum, 32); sq += __shfl_xor(sq, 32);
            float mu = sum / Cc;
            float rsg = rsqrtf(sq / Cc - mu * mu + EPS);
            #pragma unroll
            for (int ks = 0; ks < 8; ++ks) {
                #pragma unroll
                for (int e = 0; e < 8; ++e) {
                    int c = ks * 32 + lg * 8 + e;
                    float nv = (bf2f(raw[ks][e]) - mu) * rsg * n2w[c] + n2b[c];
                    ((unsigned short*)&xf[mf][ks])[e] = f2bf(nv);
                }
            }
        }
    }

    f32x4 acc2[2][8];
    #pragma unroll
    for (int mf = 0; mf < 2; ++mf)
        #pragma unroll
        for (int nf = 0; nf < 8; ++nf)
            acc2[mf][nf] = (f32x4){0.f, 0.f, 0.f, 0.f};

    for (int ch = 0; ch < 16; ++ch) {
        // ---- stage weight chunk (coalesced, 4+4 u16x8 per thread)
        {
            const unsigned short* g1 = w1t + ch * 16384;
            const unsigned short* g2 = w2t + ch * 16384;
            #pragma unroll
            for (int i = 0; i < 4; ++i) {
                int idx = (i * 512 + t) * 8;
                *(u16x8*)&w1s[idx] = *(const u16x8*)(g1 + idx);
                *(u16x8*)&w2s[idx] = *(const u16x8*)(g2 + idx);
            }
        }
        __syncthreads();
        // ---- fc1: this wave computes hid[wm*32..+32][wn*32..+32]
        {
            f32x4 acc1[2][2];
            #pragma unroll
            for (int mf = 0; mf < 2; ++mf)
                #pragma unroll
                for (int nf = 0; nf < 2; ++nf)
                    acc1[mf][nf] = (f32x4){0.f, 0.f, 0.f, 0.f};
            #pragma unroll
            for (int ks = 0; ks < 8; ++ks) {
                #pragma unroll
                for (int nf = 0; nf < 2; ++nf) {
                    int ntl = wn * 2 + nf;
                    bf16x8 bfr = *(const bf16x8*)&w1s[ntl * 4096 + ks * 512 + l * 8];
                    acc1[0][nf] = __builtin_amdgcn_mfma_f32_16x16x32_bf16(xf[0][ks], bfr, acc1[0][nf], 0, 0, 0);
                    acc1[1][nf] = __builtin_amdgcn_mfma_f32_16x16x32_bf16(xf[1][ks], bfr, acc1[1][nf], 0, 0, 0);
                }
            }
            #pragma unroll
            for (int nf = 0; nf < 2; ++nf) {
                float b1n = b1[ch * 64 + wn * 32 + nf * 16 + lr];
                #pragma unroll
                for (int mf = 0; mf < 2; ++mf)
                    #pragma unroll
                    for (int r = 0; r < 4; ++r) {
                        int m = wm * 32 + mf * 16 + lg * 4 + r;
                        hid[HIDX(m, wn * 32 + nf * 16 + lr)] =
                            f2bf(fmaxf(acc1[mf][nf][r] + b1n, 0.f));
                    }
            }
        }
        __syncthreads();
        // ---- fc2 partial: rows wm*32..+32, out cols wn*128..+128, K = this chunk's 64
        {
            bf16x8 a[2][2];
            #pragma unroll
            for (int mf = 0; mf < 2; ++mf)
                #pragma unroll
                for (int ks = 0; ks < 2; ++ks) {
                    int m = wm * 32 + mf * 16 + lr;
                    a[mf][ks] = *(const bf16x8*)&hid[HIDX(m, ks * 32 + lg * 8)];
                }
            #pragma unroll
            for (int ks = 0; ks < 2; ++ks)
                #pragma unroll
                for (int nf = 0; nf < 8; ++nf) {
                    int nt = (wn * 128 + nf * 16) >> 4;
                    bf16x8 bfr = *(const bf16x8*)&w2s[(nt * 2 + ks) * 512 + l * 8];
                    acc2[0][nf] = __builtin_amdgcn_mfma_f32_16x16x32_bf16(a[0][ks], bfr, acc2[0][nf], 0, 0, 0);
                    acc2[1][nf] = __builtin_amdgcn_mfma_f32_16x16x32_bf16(a[1][ks], bfr, acc2[1][nf], 0, 0, 0);
                }
        }
        __syncthreads();
    }

    // ---- epilogue: + b2 + residual, NCHW store (per-row image-wrap handling)
    int b0i = m0 / Lc, l0 = m0 % Lc;
    #pragma unroll
    for (int nf = 0; nf < 8; ++nf) {
        int c = wn * 128 + nf * 16 + lr;
        float b2c = b2[c];
        #pragma unroll
        for (int mf = 0; mf < 2; ++mf)
            #pragma unroll
            for (int r = 0; r < 4; ++r) {
                int m = wm * 32 + mf * 16 + lg * 4 + r;
                float res = bf2f(xs[(size_t)(m0 + m) * Cc + c]);
                int lm = l0 + m;
                int bi = b0i + (lm >= Lc);
                if (lm >= Lc) lm -= Lc;
                out[((size_t)bi * Cc + c) * Lc + lm] = acc2[mf][nf][r] + b2c + res;
            }
    }
}

// ----------------------------------------------------------------- launch
extern "C" void kernel_launch(void* const* d_in, const int* in_sizes, int n_in,
                              void* d_out, int out_size, void* d_ws, size_t ws_size,
                              hipStream_t stream) {
    const float* x      = (const float*)d_in[0];
    const float* qkv_w  = (const float*)d_in[1];
    const float* q_bias = (const float*)d_in[2];
    const float* v_bias = (const float*)d_in[3];
    const float* proj_w = (const float*)d_in[4];
    const float* proj_b = (const float*)d_in[5];
    const float* rpb    = (const float*)d_in[6];
    const float* n1w    = (const float*)d_in[7];
    const float* n1b    = (const float*)d_in[8];
    const float* n2w    = (const float*)d_in[9];
    const float* n2b    = (const float*)d_in[10];
    const float* w1     = (const float*)d_in[11];
    const float* b1     = (const float*)d_in[12];
    const float* w2     = (const float*)d_in[13];
    const float* b2     = (const float*)d_in[14];

    // ws: xw/xs bf16 51.38MB | qkvb 3KB | qkv_wb 384KB | proj_wb 128KB | w1t 512KB | w2t 512KB
    char* ws = (char*)d_ws;
    const size_t SZ_BF16 = (size_t)Mrows * Cc * 2;
    unsigned short* xw      = (unsigned short*)ws;          // xw, later xs (b,l,c)
    float*          qkvb    = (float*)(ws + SZ_BF16);
    unsigned short* qkv_wb  = (unsigned short*)(ws + SZ_BF16 + 3072);
    unsigned short* proj_wb = qkv_wb + 196608;
    unsigned short* w1t     = proj_wb + 65536;
    unsigned short* w2t     = w1t + 262144;

    // d_out scratch (fully overwritten by k_mlp_fused):
    unsigned short* qkv_s  = (unsigned short*)d_out;
    unsigned short* attn_s = qkv_s + (size_t)ROWS_G * 768;
    unsigned short* xres_s = attn_s + (size_t)ROWS_G * Cc;

    k_prep<<<1024, 256, 0, stream>>>(qkv_w, proj_w, w1, w2, q_bias, v_bias,
                                     qkv_wb, proj_wb, w1t, w2t, qkvb);

    for (int g = 0; g < NGRP; ++g) {
        unsigned short* xw_g = xw + (size_t)g * ROWS_G * Cc;
        k_ln1_part<<<GIMG * Hc, 256, 0, stream>>>(x, n1w, n1b, xw, xres_s, g * GIMG);
        k_gemm_mfma<<<dim3(ROWS_G / 128, 768 / 128), 256, 0, stream>>>(
            xw_g, qkv_wb, qkvb, qkv_s, 256, 768);
        k_attn<<<WIN_G * NHc, 256, 0, stream>>>(qkv_s, rpb, attn_s);
        k_gemm_proj<<<dim3(ROWS_G / 128, 2), 256, 0, stream>>>(
            attn_s, proj_wb, proj_b, xres_s, xw_g);
    }

    k_mlp_fused<<<Mrows / 128, 512, 0, stream>>>(xw, n2w, n2b, w1t, b1, w2t, b2,
                                                 (float*)d_out);
}

// Round 7
// 609.794 us; speedup vs baseline: 9.9299x; 1.2899x over previous
//
#include <hip/hip_runtime.h>
#include <math.h>

#define EPS 1e-5f

constexpr int Bc = 32, Cc = 256, Hc = 56, Wc = 56;
constexpr int NHc = 8, HDc = 32, WSc = 7, SSc = 3;
constexpr int NTOK = 49;
constexpr int NWIN = 64;
constexpr int Lc = Hc * Wc;                 // 3136
constexpr int Mrows = Bc * NWIN * NTOK;     // 100352
constexpr int GIMG = 8;                     // images per group
constexpr int NGRP = Bc / GIMG;             // 4
constexpr int ROWS_G = GIMG * Lc;           // 25088
constexpr int WIN_G = GIMG * NWIN;          // 512

typedef short bf16x8 __attribute__((ext_vector_type(8)));
typedef float f32x4 __attribute__((ext_vector_type(4)));
typedef unsigned short u16x8 __attribute__((ext_vector_type(8)));

__device__ __forceinline__ float bf2f(unsigned short u) {
    return __uint_as_float(((unsigned)u) << 16);
}
__device__ __forceinline__ unsigned short f2bf(float f) {
    unsigned x = __float_as_uint(f);
    return (unsigned short)((x + 0x7fffu + ((x >> 16) & 1u)) >> 16);  // RNE
}

// ------------------------------------------------ weight prep
__global__ __launch_bounds__(256) void k_prep(const float* __restrict__ qkv_w,
                                              const float* __restrict__ proj_w,
                                              const float* __restrict__ w1,
                                              const float* __restrict__ w2,
                                              const float* __restrict__ qb,
                                              const float* __restrict__ vb,
                                              unsigned short* __restrict__ qkv_wb,
                                              unsigned short* __restrict__ proj_wb,
                                              unsigned short* __restrict__ w1t,
                                              unsigned short* __restrict__ w2t,
                                              float* __restrict__ qkvb) {
    int i = blockIdx.x * 256 + threadIdx.x;
    if (i < 768) qkvb[i] = (i < 256) ? qb[i] : ((i < 512) ? 0.f : vb[i - 512]);
    if (i < 196608) qkv_wb[i] = f2bf(qkv_w[i]);
    if (i < 65536)  proj_wb[i] = f2bf(proj_w[i]);
    if (i < 262144) {
        int n1 = i >> 8, k1 = i & 255;       // w1: (1024, 256)
        w1t[((n1 >> 4) * 32 + (k1 >> 3)) * 128 + (n1 & 15) * 8 + (k1 & 7)] = f2bf(w1[i]);
        int n2 = i >> 10, k2 = i & 1023;     // w2: (256, 1024)
        w2t[((k2 >> 6) * 32 + (n2 >> 4) * 2 + ((k2 >> 5) & 1)) * 512 +
            ((k2 >> 3) & 3) * 128 + (n2 & 15) * 8 + (k2 & 7)] = f2bf(w2[i]);
    }
}

// ------------------------------------------------ LN1 + roll + window partition (per group)
__global__ __launch_bounds__(256) void k_ln1_part(const float* __restrict__ x,
                                                  const float* __restrict__ n1w,
                                                  const float* __restrict__ n1b,
                                                  unsigned short* __restrict__ xw,
                                                  unsigned short* __restrict__ xres,
                                                  int b0) {
    __shared__ float s[Cc * 57];
    __shared__ float mu[Wc], rs[Wc];
    int bg = blockIdx.x / Hc, h = blockIdx.x % Hc;
    int b = b0 + bg;
    int t = threadIdx.x;
    const float* xp = x + ((size_t)b * Cc) * Lc + h * Wc;
    for (int idx = t; idx < Cc * Wc; idx += 256) {
        int c = idx / Wc, w = idx % Wc;
        s[c * 57 + w] = xp[(size_t)c * Lc + w];
    }
    __syncthreads();
    int lane = t & 63, wv = t >> 6;
    for (int p = wv; p < Wc; p += 4) {
        float sum = 0.f, sq = 0.f;
        #pragma unroll
        for (int k = 0; k < 4; ++k) {
            float v = s[(lane + 64 * k) * 57 + p];
            sum += v; sq += v * v;
        }
        #pragma unroll
        for (int off = 32; off; off >>= 1) {
            sum += __shfl_xor(sum, off);
            sq  += __shfl_xor(sq, off);
        }
        if (lane == 0) {
            float m = sum / Cc;
            mu[p] = m;
            rs[p] = rsqrtf(sq / Cc - m * m + EPS);
        }
    }
    __syncthreads();
    float wc_ = n1w[t], bc_ = n1b[t];
    int hr = (h + Hc - SSc) % Hc;
    int whh = hr / WSc, th = hr % WSc;
    for (int p = 0; p < Wc; ++p) {
        float raw = s[t * 57 + p];
        xres[((size_t)bg * Lc + h * Wc + p) * Cc + t] = f2bf(raw);
        int wr = (p + Wc - SSc) % Wc;
        int www = wr / WSc, tw = wr % WSc;
        int row = (b * NWIN + whh * 8 + www) * NTOK + th * WSc + tw;
        float v = (raw - mu[p]) * rs[p] * wc_ + bc_;
        xw[(size_t)row * Cc + t] = f2bf(v);
    }
}

// ------------------------------------------------ MFMA GEMM (qkv): out = A @ W^T + bias -> bf16
__global__ __launch_bounds__(256) void k_gemm_mfma(const unsigned short* __restrict__ A,
                                                   const unsigned short* __restrict__ W,
                                                   const float* __restrict__ bias,
                                                   unsigned short* __restrict__ outb,
                                                   int K, int Nd) {
    __shared__ unsigned short As[128 * 32];
    __shared__ unsigned short Bs[128 * 32];
    int t = threadIdx.x;
    int l = t & 63, w = t >> 6;
    int wm = w & 1, wn = w >> 1;
    int m0 = blockIdx.x * 128, n0 = blockIdx.y * 128;
    int lr = l & 15, lg = l >> 4;

    f32x4 acc[4][4];
    #pragma unroll
    for (int i = 0; i < 4; ++i)
        #pragma unroll
        for (int j = 0; j < 4; ++j)
            acc[i][j] = (f32x4){0.f, 0.f, 0.f, 0.f};

    for (int kt = 0; kt < K; kt += 32) {
        #pragma unroll
        for (int s = 0; s < 2; ++s) {
            int cid = t + s * 256;
            int row = cid >> 2, ch = cid & 3;
            u16x8 va = *(const u16x8*)(A + (size_t)(m0 + row) * K + kt + ch * 8);
            u16x8 vb = *(const u16x8*)(W + (size_t)(n0 + row) * K + kt + ch * 8);
            int off = (row * 32 + ch * 8) ^ ((row & 7) << 3);
            *(u16x8*)&As[off] = va;
            *(u16x8*)&Bs[off] = vb;
        }
        __syncthreads();
        bf16x8 af[4], bfr[4];
        #pragma unroll
        for (int i = 0; i < 4; ++i) {
            int ra = wm * 64 + i * 16 + lr;
            af[i] = *(bf16x8*)&As[(ra * 32 + lg * 8) ^ ((ra & 7) << 3)];
            int rb = wn * 64 + i * 16 + lr;
            bfr[i] = *(bf16x8*)&Bs[(rb * 32 + lg * 8) ^ ((rb & 7) << 3)];
        }
        #pragma unroll
        for (int i = 0; i < 4; ++i)
            #pragma unroll
            for (int j = 0; j < 4; ++j)
                acc[i][j] = __builtin_amdgcn_mfma_f32_16x16x32_bf16(af[i], bfr[j], acc[i][j], 0, 0, 0);
        __syncthreads();
    }

    float bj[4];
    #pragma unroll
    for (int j = 0; j < 4; ++j) bj[j] = bias[n0 + wn * 64 + j * 16 + lr];
    #pragma unroll
    for (int i = 0; i < 4; ++i)
        #pragma unroll
        for (int j = 0; j < 4; ++j) {
            int col = n0 + wn * 64 + j * 16 + lr;
            #pragma unroll
            for (int r = 0; r < 4; ++r) {
                int row = m0 + wm * 64 + i * 16 + lg * 4 + r;
                outb[(size_t)row * Nd + col] = f2bf(acc[i][j][r] + bj[j]);
            }
        }
}

// ------------------------------------------------ proj GEMM + fused window-reverse/unshift/residual
__global__ __launch_bounds__(256) void k_gemm_proj(const unsigned short* __restrict__ A,
                                                   const unsigned short* __restrict__ W,
                                                   const float* __restrict__ bias,
                                                   const unsigned short* __restrict__ xres,
                                                   unsigned short* __restrict__ xs) {
    __shared__ unsigned short As[128 * 32];
    __shared__ unsigned short Bs[128 * 32];
    constexpr int K = 256;
    int t = threadIdx.x;
    int l = t & 63, w = t >> 6;
    int wm = w & 1, wn = w >> 1;
    int m0 = blockIdx.x * 128, n0 = blockIdx.y * 128;
    int lr = l & 15, lg = l >> 4;

    f32x4 acc[4][4];
    #pragma unroll
    for (int i = 0; i < 4; ++i)
        #pragma unroll
        for (int j = 0; j < 4; ++j)
            acc[i][j] = (f32x4){0.f, 0.f, 0.f, 0.f};

    for (int kt = 0; kt < K; kt += 32) {
        #pragma unroll
        for (int s = 0; s < 2; ++s) {
            int cid = t + s * 256;
            int row = cid >> 2, ch = cid & 3;
            u16x8 va = *(const u16x8*)(A + (size_t)(m0 + row) * K + kt + ch * 8);
            u16x8 vb = *(const u16x8*)(W + (size_t)(n0 + row) * K + kt + ch * 8);
            int off = (row * 32 + ch * 8) ^ ((row & 7) << 3);
            *(u16x8*)&As[off] = va;
            *(u16x8*)&Bs[off] = vb;
        }
        __syncthreads();
        bf16x8 af[4], bfr[4];
        #pragma unroll
        for (int i = 0; i < 4; ++i) {
            int ra = wm * 64 + i * 16 + lr;
            af[i] = *(bf16x8*)&As[(ra * 32 + lg * 8) ^ ((ra & 7) << 3)];
            int rb = wn * 64 + i * 16 + lr;
            bfr[i] = *(bf16x8*)&Bs[(rb * 32 + lg * 8) ^ ((rb & 7) << 3)];
        }
        #pragma unroll
        for (int i = 0; i < 4; ++i)
            #pragma unroll
            for (int j = 0; j < 4; ++j)
                acc[i][j] = __builtin_amdgcn_mfma_f32_16x16x32_bf16(af[i], bfr[j], acc[i][j], 0, 0, 0);
        __syncthreads();
    }

    float bj[4];
    #pragma unroll
    for (int j = 0; j < 4; ++j) bj[j] = bias[n0 + wn * 64 + j * 16 + lr];
    #pragma unroll
    for (int i = 0; i < 4; ++i)
        #pragma unroll
        for (int j = 0; j < 4; ++j) {
            int col = n0 + wn * 64 + j * 16 + lr;
            #pragma unroll
            for (int r = 0; r < 4; ++r) {
                int row = m0 + wm * 64 + i * 16 + lg * 4 + r;   // group-local window row
                int wl = row / NTOK, tok = row - wl * NTOK;
                int bg = wl >> 6, wi = wl & 63;
                int hr = (wi >> 3) * 7 + tok / 7;
                int wr = (wi & 7) * 7 + tok % 7;
                int hh = hr + SSc; if (hh >= Hc) hh -= Hc;
                int ww = wr + SSc; if (ww >= Wc) ww -= Wc;
                size_t didx = ((size_t)bg * Lc + hh * Wc + ww) * Cc + col;
                float res = bf2f(xres[didx]);
                xs[didx] = f2bf(res + acc[i][j][r] + bj[j]);
            }
        }
}

// ------------------------------------------------ window attention v3: MFMA, 1 wave per (window, head)
// LDS per wave (12KB): [0..4095] Q[64][32]+K[64][32] swizzled, overlaid by P[64][64] after QK;
// [4096..6143] Vt[32][64] swizzled. Block-shared rpb table (bf16). No post-stage barriers.
__global__ __launch_bounds__(256) void k_attn(const unsigned short* __restrict__ qkv,
                                              const float* __restrict__ rpb,
                                              unsigned short* __restrict__ outb) {
    __shared__ unsigned short lds[4 * 6144 + 1352];
    unsigned short* rpbs = &lds[4 * 6144];
    int t = threadIdx.x;
    int w = t >> 6, l = t & 63;
    int lr = l & 15, lg = l >> 4;
    unsigned short* wl = &lds[w * 6144];
    unsigned short* Qs = wl;
    unsigned short* Ks = wl + 2048;
    unsigned short* Pm = wl;            // overlays Q/K after QK MFMA
    unsigned short* Vt = wl + 4096;

    for (int i = t; i < 1352; i += 256) rpbs[i] = f2bf(rpb[i]);

    int gid = blockIdx.x * 4 + w;
    int b_ = gid >> 3, hh = gid & 7;
    const unsigned short* base = qkv + (size_t)b_ * NTOK * 768 + hh * HDc;

    // ---- stage Q, K rows (lane = row), V scattered transposed
    {
        int j = l;
        u16x8 vq[4], vk[4], vv[4];
        if (j < NTOK) {
            const unsigned short* rp = base + j * 768;
            #pragma unroll
            for (int s = 0; s < 4; ++s) {
                vq[s] = *(const u16x8*)(rp + s * 8);
                vk[s] = *(const u16x8*)(rp + 256 + s * 8);
                vv[s] = *(const u16x8*)(rp + 512 + s * 8);
            }
        } else {
            u16x8 z = {0, 0, 0, 0, 0, 0, 0, 0};
            #pragma unroll
            for (int s = 0; s < 4; ++s) { vq[s] = z; vk[s] = z; vv[s] = z; }
        }
        #pragma unroll
        for (int s = 0; s < 4; ++s) {
            int off = (j * 32 + s * 8) ^ ((j & 7) << 3);
            *(u16x8*)&Qs[off] = vq[s];
            *(u16x8*)&Ks[off] = vk[s];
        }
        #pragma unroll
        for (int s = 0; s < 4; ++s)
            #pragma unroll
            for (int e = 0; e < 8; ++e) {
                int d = s * 8 + e;
                Vt[d * 64 + (j ^ ((d & 7) << 3))] = ((unsigned short*)&vv[s])[e];
            }
    }
    __syncthreads();   // rpbs visibility (per-wave Q/K/V needs no cross-wave sync)

    // ---- QK^T: S[i][j], i/j over 64 (padded)
    bf16x8 aq[4], bk[4];
    #pragma unroll
    for (int mt = 0; mt < 4; ++mt) {
        int row = mt * 16 + lr;
        int off = (row * 32 + lg * 8) ^ ((row & 7) << 3);
        aq[mt] = *(bf16x8*)&Qs[off];
        bk[mt] = *(bf16x8*)&Ks[off];
    }
    f32x4 sc[4][4];
    #pragma unroll
    for (int mt = 0; mt < 4; ++mt)
        #pragma unroll
        for (int nt = 0; nt < 4; ++nt)
            sc[mt][nt] = __builtin_amdgcn_mfma_f32_16x16x32_bf16(
                aq[mt], bk[nt], (f32x4){0.f, 0.f, 0.f, 0.f}, 0, 0, 0);

    // ---- per-lane geometry
    const float scale = 0.17677669529663687f;
    int wi = b_ & 63, wh = wi >> 3, wwc = wi & 7;
    int jh[4], jw[4], ridJ[4];
    #pragma unroll
    for (int nt = 0; nt < 4; ++nt) {
        int j = nt * 16 + lr;
        jh[nt] = j / 7; jw[nt] = j - jh[nt] * 7;
        int gh = wh * 7 + jh[nt], gw = wwc * 7 + jw[nt];
        int rh = gh < 49 ? 0 : (gh < 53 ? 1 : 2);
        int rw = gw < 49 ? 0 : (gw < 53 ? 1 : 2);
        ridJ[nt] = rh * 3 + rw;
    }

    // ---- bias + mask + softmax (row-reduce over lr group), write P (bf16, unnormalized)
    float rowrcp[4][4];
    #pragma unroll
    for (int mt = 0; mt < 4; ++mt) {
        #pragma unroll
        for (int r = 0; r < 4; ++r) {
            int i = mt * 16 + lg * 4 + r;
            int ih = i / 7, iw = i - ih * 7;
            int gh = wh * 7 + ih, gw = wwc * 7 + iw;
            int rhI = gh < 49 ? 0 : (gh < 53 ? 1 : 2);
            int rwI = gw < 49 ? 0 : (gw < 53 ? 1 : 2);
            int ridI = rhI * 3 + rwI;
            bool ivalid = (i < NTOK);
            float vals[4];
            float vmax = -1e30f;
            #pragma unroll
            for (int nt = 0; nt < 4; ++nt) {
                int j = nt * 16 + lr;
                float v = -1e30f;
                if (ivalid && j < NTOK) {
                    int rpi = (ih - jh[nt] + 6) * 13 + (iw - jw[nt] + 6);
                    float bv = bf2f(rpbs[rpi * 8 + hh]);
                    float msk = (ridI == ridJ[nt]) ? 0.f : -100.f;
                    v = sc[mt][nt][r] * scale + bv + msk;
                }
                vals[nt] = v;
                vmax = fmaxf(vmax, v);
            }
            #pragma unroll
            for (int off = 1; off < 16; off <<= 1)
                vmax = fmaxf(vmax, __shfl_xor(vmax, off));
            float s = 0.f;
            unsigned short pb[4];
            #pragma unroll
            for (int nt = 0; nt < 4; ++nt) {
                float e = (vals[nt] > -1e29f) ? __expf(vals[nt] - vmax) : 0.f;
                s += e;
                pb[nt] = f2bf(e);
            }
            #pragma unroll
            for (int off = 1; off < 16; off <<= 1)
                s += __shfl_xor(s, off);
            rowrcp[mt][r] = 1.f / s;
            #pragma unroll
            for (int nt = 0; nt < 4; ++nt) {
                int j = nt * 16 + lr;
                Pm[(i * 64 + j) ^ ((i & 7) << 3)] = pb[nt];
            }
        }
    }

    // ---- PV: out[i][d] = sum_j P[i][j] V[j][d], K=64 (2 ksteps)
    f32x4 o[4][2];
    #pragma unroll
    for (int mt = 0; mt < 4; ++mt)
        #pragma unroll
        for (int nt = 0; nt < 2; ++nt)
            o[mt][nt] = (f32x4){0.f, 0.f, 0.f, 0.f};
    #pragma unroll
    for (int ks = 0; ks < 2; ++ks) {
        bf16x8 ap[4], bv2[2];
        #pragma unroll
        for (int mt = 0; mt < 4; ++mt) {
            int row = mt * 16 + lr;
            ap[mt] = *(bf16x8*)&Pm[(row * 64 + ks * 32 + lg * 8) ^ ((row & 7) << 3)];
        }
        #pragma unroll
        for (int nt = 0; nt < 2; ++nt) {
            int n = nt * 16 + lr;
            bv2[nt] = *(bf16x8*)&Vt[(n * 64 + ks * 32 + lg * 8) ^ ((n & 7) << 3)];
        }
        #pragma unroll
        for (int mt = 0; mt < 4; ++mt)
            #pragma unroll
            for (int nt = 0; nt < 2; ++nt)
                o[mt][nt] = __builtin_amdgcn_mfma_f32_16x16x32_bf16(ap[mt], bv2[nt], o[mt][nt], 0, 0, 0);
    }

    // ---- normalize + store rows i < 49
    #pragma unroll
    for (int mt = 0; mt < 4; ++mt)
        #pragma unroll
        for (int r = 0; r < 4; ++r) {
            int i = mt * 16 + lg * 4 + r;
            if (i < NTOK) {
                float rc = rowrcp[mt][r];
                #pragma unroll
                for (int nt = 0; nt < 2; ++nt) {
                    int d = nt * 16 + lr;
                    outb[((size_t)b_ * NTOK + i) * Cc + hh * HDc + d] = f2bf(o[mt][nt][r] * rc);
                }
            }
        }
}

// ------------------------------------------------ fused LN2 + MLP v4 + residual + NCHW out
// 128 rows/block, 512 threads. v4: register prefetch of next weight chunk (T14 async-STAGE)
// so the L2 latency hides under fc1+fc2 MFMA instead of being serially exposed per chunk.
#define HIDX(m, c) (((m) * 64 + (c)) ^ (((m) & 7) << 3))
__global__ __launch_bounds__(512) void k_mlp_fused(const unsigned short* __restrict__ xs,
                                                   const float* __restrict__ n2w,
                                                   const float* __restrict__ n2b,
                                                   const unsigned short* __restrict__ w1t,
                                                   const float* __restrict__ b1,
                                                   const unsigned short* __restrict__ w2t,
                                                   const float* __restrict__ b2,
                                                   float* __restrict__ out) {
    __shared__ unsigned short w1s[16384];
    __shared__ unsigned short w2s[16384];
    __shared__ unsigned short hid[8192];
    int t = threadIdx.x;
    int l = t & 63, w = t >> 6;
    int wm = w >> 1, wn = w & 1;
    int lr = l & 15, lg = l >> 4;
    int m0 = blockIdx.x * 128;

    // ---- Phase A (registers only): load 2 rows/lane, LN2, build bf16 A-frags
    bf16x8 xf[2][8];
    {
        #pragma unroll
        for (int mf = 0; mf < 2; ++mf) {
            int row = m0 + wm * 32 + mf * 16 + lr;
            const unsigned short* xrow = xs + (size_t)row * Cc;
            u16x8 raw[8];
            float sum = 0.f, sq = 0.f;
            #pragma unroll
            for (int ks = 0; ks < 8; ++ks) {
                raw[ks] = *(const u16x8*)(xrow + ks * 32 + lg * 8);
                #pragma unroll
                for (int e = 0; e < 8; ++e) {
                    float f = bf2f(raw[ks][e]);
                    sum += f; sq += f * f;
                }
            }
            sum += __shfl_xor(sum, 16); sq += __shfl_xor(sq, 16);
            sum += __shfl_xor(sum, 32); sq += __shfl_xor(sq, 32);
            float mu = sum / Cc;
            float rsg = rsqrtf(sq / Cc - mu * mu + EPS);
            #pragma unroll
            for (int ks = 0; ks < 8; ++ks) {
                #pragma unroll
                for (int e = 0; e < 8; ++e) {
                    int c = ks * 32 + lg * 8 + e;
                    float nv = (bf2f(raw[ks][e]) - mu) * rsg * n2w[c] + n2b[c];
                    ((unsigned short*)&xf[mf][ks])[e] = f2bf(nv);
                }
            }
        }
    }

    f32x4 acc2[2][8];
    #pragma unroll
    for (int mf = 0; mf < 2; ++mf)
        #pragma unroll
        for (int nf = 0; nf < 8; ++nf)
            acc2[mf][nf] = (f32x4){0.f, 0.f, 0.f, 0.f};

    // prefetch chunk 0
    u16x8 p1[4], p2[4];
    #pragma unroll
    for (int i = 0; i < 4; ++i) {
        int idx = (i * 512 + t) * 8;
        p1[i] = *(const u16x8*)(w1t + idx);
        p2[i] = *(const u16x8*)(w2t + idx);
    }

    for (int ch = 0; ch < 16; ++ch) {
        // ---- commit prefetched chunk to LDS
        #pragma unroll
        for (int i = 0; i < 4; ++i) {
            int idx = (i * 512 + t) * 8;
            *(u16x8*)&w1s[idx] = p1[i];
            *(u16x8*)&w2s[idx] = p2[i];
        }
        __syncthreads();
        // ---- issue prefetch for chunk ch+1 (completes under fc1+fc2)
        if (ch < 15) {
            const unsigned short* n1 = w1t + (ch + 1) * 16384;
            const unsigned short* n2 = w2t + (ch + 1) * 16384;
            #pragma unroll
            for (int i = 0; i < 4; ++i) {
                int idx = (i * 512 + t) * 8;
                p1[i] = *(const u16x8*)(n1 + idx);
                p2[i] = *(const u16x8*)(n2 + idx);
            }
        }
        // ---- fc1: hid[wm*32..+32][wn*32..+32]
        {
            f32x4 acc1[2][2];
            #pragma unroll
            for (int mf = 0; mf < 2; ++mf)
                #pragma unroll
                for (int nf = 0; nf < 2; ++nf)
                    acc1[mf][nf] = (f32x4){0.f, 0.f, 0.f, 0.f};
            #pragma unroll
            for (int ks = 0; ks < 8; ++ks) {
                #pragma unroll
                for (int nf = 0; nf < 2; ++nf) {
                    int ntl = wn * 2 + nf;
                    bf16x8 bfr = *(const bf16x8*)&w1s[ntl * 4096 + ks * 512 + l * 8];
                    acc1[0][nf] = __builtin_amdgcn_mfma_f32_16x16x32_bf16(xf[0][ks], bfr, acc1[0][nf], 0, 0, 0);
                    acc1[1][nf] = __builtin_amdgcn_mfma_f32_16x16x32_bf16(xf[1][ks], bfr, acc1[1][nf], 0, 0, 0);
                }
            }
            #pragma unroll
            for (int nf = 0; nf < 2; ++nf) {
                float b1n = b1[ch * 64 + wn * 32 + nf * 16 + lr];
                #pragma unroll
                for (int mf = 0; mf < 2; ++mf)
                    #pragma unroll
                    for (int r = 0; r < 4; ++r) {
                        int m = wm * 32 + mf * 16 + lg * 4 + r;
                        hid[HIDX(m, wn * 32 + nf * 16 + lr)] =
                            f2bf(fmaxf(acc1[mf][nf][r] + b1n, 0.f));
                    }
            }
        }
        __syncthreads();
        // ---- fc2 partial over this chunk's 64 h-dims
        {
            bf16x8 a[2][2];
            #pragma unroll
            for (int mf = 0; mf < 2; ++mf)
                #pragma unroll
                for (int ks = 0; ks < 2; ++ks) {
                    int m = wm * 32 + mf * 16 + lr;
                    a[mf][ks] = *(const bf16x8*)&hid[HIDX(m, ks * 32 + lg * 8)];
                }
            #pragma unroll
            for (int ks = 0; ks < 2; ++ks)
                #pragma unroll
                for (int nf = 0; nf < 8; ++nf) {
                    int nt = (wn * 128 + nf * 16) >> 4;
                    bf16x8 bfr = *(const bf16x8*)&w2s[(nt * 2 + ks) * 512 + l * 8];
                    acc2[0][nf] = __builtin_amdgcn_mfma_f32_16x16x32_bf16(a[0][ks], bfr, acc2[0][nf], 0, 0, 0);
                    acc2[1][nf] = __builtin_amdgcn_mfma_f32_16x16x32_bf16(a[1][ks], bfr, acc2[1][nf], 0, 0, 0);
                }
        }
        __syncthreads();
    }

    // ---- epilogue: + b2 + residual, NCHW store
    int b0i = m0 / Lc, l0 = m0 % Lc;
    #pragma unroll
    for (int nf = 0; nf < 8; ++nf) {
        int c = wn * 128 + nf * 16 + lr;
        float b2c = b2[c];
        #pragma unroll
        for (int mf = 0; mf < 2; ++mf)
            #pragma unroll
            for (int r = 0; r < 4; ++r) {
                int m = wm * 32 + mf * 16 + lg * 4 + r;
                float res = bf2f(xs[(size_t)(m0 + m) * Cc + c]);
                int lm = l0 + m;
                int bi = b0i + (lm >= Lc);
                if (lm >= Lc) lm -= Lc;
                out[((size_t)bi * Cc + c) * Lc + lm] = acc2[mf][nf][r] + b2c + res;
            }
    }
}

// ----------------------------------------------------------------- launch
extern "C" void kernel_launch(void* const* d_in, const int* in_sizes, int n_in,
                              void* d_out, int out_size, void* d_ws, size_t ws_size,
                              hipStream_t stream) {
    const float* x      = (const float*)d_in[0];
    const float* qkv_w  = (const float*)d_in[1];
    const float* q_bias = (const float*)d_in[2];
    const float* v_bias = (const float*)d_in[3];
    const float* proj_w = (const float*)d_in[4];
    const float* proj_b = (const float*)d_in[5];
    const float* rpb    = (const float*)d_in[6];
    const float* n1w    = (const float*)d_in[7];
    const float* n1b    = (const float*)d_in[8];
    const float* n2w    = (const float*)d_in[9];
    const float* n2b    = (const float*)d_in[10];
    const float* w1     = (const float*)d_in[11];
    const float* b1     = (const float*)d_in[12];
    const float* w2     = (const float*)d_in[13];
    const float* b2     = (const float*)d_in[14];

    char* ws = (char*)d_ws;
    const size_t SZ_BF16 = (size_t)Mrows * Cc * 2;
    unsigned short* xw      = (unsigned short*)ws;          // xw, later xs (b,l,c)
    float*          qkvb    = (float*)(ws + SZ_BF16);
    unsigned short* qkv_wb  = (unsigned short*)(ws + SZ_BF16 + 3072);
    unsigned short* proj_wb = qkv_wb + 196608;
    unsigned short* w1t     = proj_wb + 65536;
    unsigned short* w2t     = w1t + 262144;

    unsigned short* qkv_s  = (unsigned short*)d_out;
    unsigned short* attn_s = qkv_s + (size_t)ROWS_G * 768;
    unsigned short* xres_s = attn_s + (size_t)ROWS_G * Cc;

    k_prep<<<1024, 256, 0, stream>>>(qkv_w, proj_w, w1, w2, q_bias, v_bias,
                                     qkv_wb, proj_wb, w1t, w2t, qkvb);

    for (int g = 0; g < NGRP; ++g) {
        unsigned short* xw_g = xw + (size_t)g * ROWS_G * Cc;
        k_ln1_part<<<GIMG * Hc, 256, 0, stream>>>(x, n1w, n1b, xw, xres_s, g * GIMG);
        k_gemm_mfma<<<dim3(ROWS_G / 128, 768 / 128), 256, 0, stream>>>(
            xw_g, qkv_wb, qkvb, qkv_s, 256, 768);
        k_attn<<<WIN_G * NHc / 4, 256, 0, stream>>>(qkv_s, rpb, attn_s);
        k_gemm_proj<<<dim3(ROWS_G / 128, 2), 256, 0, stream>>>(
            attn_s, proj_wb, proj_b, xres_s, xw_g);
    }

    k_mlp_fused<<<Mrows / 128, 512, 0, stream>>>(xw, n2w, n2b, w1t, b1, w2t, b2,
                                                 (float*)d_out);
}

// Round 8
// 567.174 us; speedup vs baseline: 10.6761x; 1.0751x over previous
//
#include <hip/hip_runtime.h>
#include <math.h>

#define EPS 1e-5f

constexpr int Bc = 32, Cc = 256, Hc = 56, Wc = 56;
constexpr int NHc = 8, HDc = 32, WSc = 7, SSc = 3;
constexpr int NTOK = 49;
constexpr int NWIN = 64;
constexpr int Lc = Hc * Wc;                 // 3136
constexpr int Mrows = Bc * NWIN * NTOK;     // 100352
constexpr int GIMG = 8;                     // images per group
constexpr int NGRP = Bc / GIMG;             // 4
constexpr int ROWS_G = GIMG * Lc;           // 25088
constexpr int WIN_G = GIMG * NWIN;          // 512

typedef short bf16x8 __attribute__((ext_vector_type(8)));
typedef float f32x4 __attribute__((ext_vector_type(4)));
typedef unsigned short u16x8 __attribute__((ext_vector_type(8)));
typedef unsigned short u16x4 __attribute__((ext_vector_type(4)));

__device__ __forceinline__ float bf2f(unsigned short u) {
    return __uint_as_float(((unsigned)u) << 16);
}
__device__ __forceinline__ unsigned short f2bf(float f) {
    unsigned x = __float_as_uint(f);
    return (unsigned short)((x + 0x7fffu + ((x >> 16) & 1u)) >> 16);  // RNE
}
__device__ __forceinline__ void gload_lds16(const void* g, void* l) {
    __builtin_amdgcn_global_load_lds(
        (const __attribute__((address_space(1))) unsigned int*)g,
        (__attribute__((address_space(3))) unsigned int*)l, 16, 0, 0);
}
// inverse of block-swizzle B' = B ^ ((B>>2)&7)
__device__ __forceinline__ void inv_swz(int bp, int& row, int& ch) {
    int b2 = ((bp >> 2) ^ (bp >> 4)) & 1;
    int b1_ = ((bp >> 1) ^ (bp >> 3)) & 1;
    int b0 = (bp ^ (bp >> 2) ^ (bp >> 4)) & 1;
    int B = (bp & ~7) | (b2 << 2) | (b1_ << 1) | b0;
    row = B >> 2; ch = B & 3;
}

// ------------------------------------------------ weight prep
__global__ __launch_bounds__(256) void k_prep(const float* __restrict__ qkv_w,
                                              const float* __restrict__ proj_w,
                                              const float* __restrict__ w1,
                                              const float* __restrict__ w2,
                                              const float* __restrict__ qb,
                                              const float* __restrict__ vb,
                                              unsigned short* __restrict__ qkv_wb,
                                              unsigned short* __restrict__ proj_wb,
                                              unsigned short* __restrict__ w1t,
                                              unsigned short* __restrict__ w2t,
                                              float* __restrict__ qkvb) {
    int i = blockIdx.x * 256 + threadIdx.x;
    if (i < 768) qkvb[i] = (i < 256) ? qb[i] : ((i < 512) ? 0.f : vb[i - 512]);
    if (i < 196608) qkv_wb[i] = f2bf(qkv_w[i]);
    if (i < 65536)  proj_wb[i] = f2bf(proj_w[i]);
    if (i < 262144) {
        int n1 = i >> 8, k1 = i & 255;       // w1: (1024, 256)
        w1t[((n1 >> 4) * 32 + (k1 >> 3)) * 128 + (n1 & 15) * 8 + (k1 & 7)] = f2bf(w1[i]);
        int n2 = i >> 10, k2 = i & 1023;     // w2: (256, 1024)
        w2t[((k2 >> 6) * 32 + (n2 >> 4) * 2 + ((k2 >> 5) & 1)) * 512 +
            ((k2 >> 3) & 3) * 128 + (n2 & 15) * 8 + (k2 & 7)] = f2bf(w2[i]);
    }
}

// ------------------------------------------------ LN1 + roll + window partition (per group)
__global__ __launch_bounds__(256) void k_ln1_part(const float* __restrict__ x,
                                                  const float* __restrict__ n1w,
                                                  const float* __restrict__ n1b,
                                                  unsigned short* __restrict__ xw,
                                                  unsigned short* __restrict__ xres,
                                                  int b0) {
    __shared__ float s[Cc * 57];
    __shared__ float mu[Wc], rs[Wc];
    int bg = blockIdx.x / Hc, h = blockIdx.x % Hc;
    int b = b0 + bg;
    int t = threadIdx.x;
    const float* xp = x + ((size_t)b * Cc) * Lc + h * Wc;
    for (int idx = t; idx < Cc * Wc; idx += 256) {
        int c = idx / Wc, w = idx % Wc;
        s[c * 57 + w] = xp[(size_t)c * Lc + w];
    }
    __syncthreads();
    int lane = t & 63, wv = t >> 6;
    for (int p = wv; p < Wc; p += 4) {
        float sum = 0.f, sq = 0.f;
        #pragma unroll
        for (int k = 0; k < 4; ++k) {
            float v = s[(lane + 64 * k) * 57 + p];
            sum += v; sq += v * v;
        }
        #pragma unroll
        for (int off = 32; off; off >>= 1) {
            sum += __shfl_xor(sum, off);
            sq  += __shfl_xor(sq, off);
        }
        if (lane == 0) {
            float m = sum / Cc;
            mu[p] = m;
            rs[p] = rsqrtf(sq / Cc - m * m + EPS);
        }
    }
    __syncthreads();
    float wc_ = n1w[t], bc_ = n1b[t];
    int hr = (h + Hc - SSc) % Hc;
    int whh = hr / WSc, th = hr % WSc;
    for (int p = 0; p < Wc; ++p) {
        float raw = s[t * 57 + p];
        xres[((size_t)bg * Lc + h * Wc + p) * Cc + t] = f2bf(raw);
        int wr = (p + Wc - SSc) % Wc;
        int www = wr / WSc, tw = wr % WSc;
        int row = (b * NWIN + whh * 8 + www) * NTOK + th * WSc + tw;
        float v = (raw - mu[p]) * rs[p] * wc_ + bc_;
        xw[(size_t)row * Cc + t] = f2bf(v);
    }
}

// ------------------------------------------------ MFMA GEMM (qkv), global_load_lds staging
__global__ __launch_bounds__(256) void k_gemm_mfma(const unsigned short* __restrict__ A,
                                                   const unsigned short* __restrict__ W,
                                                   const float* __restrict__ bias,
                                                   unsigned short* __restrict__ outb,
                                                   int K, int Nd) {
    __shared__ unsigned short As[128 * 32];
    __shared__ unsigned short Bs[128 * 32];
    int t = threadIdx.x;
    int l = t & 63, w = t >> 6;
    int wm = w & 1, wn = w >> 1;
    int m0 = blockIdx.x * 128, n0 = blockIdx.y * 128;
    int lr = l & 15, lg = l >> 4;

    int row0, ch0, row1, ch1;
    inv_swz(w * 128 + l, row0, ch0);
    inv_swz(w * 128 + 64 + l, row1, ch1);
    const unsigned short* gA0 = A + (size_t)(m0 + row0) * K + ch0 * 8;
    const unsigned short* gA1 = A + (size_t)(m0 + row1) * K + ch1 * 8;
    const unsigned short* gB0 = W + (size_t)(n0 + row0) * K + ch0 * 8;
    const unsigned short* gB1 = W + (size_t)(n0 + row1) * K + ch1 * 8;
    unsigned short* lA0 = &As[(w * 128) * 8];
    unsigned short* lA1 = &As[(w * 128 + 64) * 8];
    unsigned short* lB0 = &Bs[(w * 128) * 8];
    unsigned short* lB1 = &Bs[(w * 128 + 64) * 8];

    f32x4 acc[4][4];
    #pragma unroll
    for (int i = 0; i < 4; ++i)
        #pragma unroll
        for (int j = 0; j < 4; ++j)
            acc[i][j] = (f32x4){0.f, 0.f, 0.f, 0.f};

    for (int kt = 0; kt < K; kt += 32) {
        gload_lds16(gA0 + kt, lA0);
        gload_lds16(gA1 + kt, lA1);
        gload_lds16(gB0 + kt, lB0);
        gload_lds16(gB1 + kt, lB1);
        __syncthreads();
        bf16x8 af[4], bfr[4];
        #pragma unroll
        for (int i = 0; i < 4; ++i) {
            int ra = wm * 64 + i * 16 + lr;
            af[i] = *(bf16x8*)&As[(ra * 32 + lg * 8) ^ ((ra & 7) << 3)];
            int rb = wn * 64 + i * 16 + lr;
            bfr[i] = *(bf16x8*)&Bs[(rb * 32 + lg * 8) ^ ((rb & 7) << 3)];
        }
        #pragma unroll
        for (int i = 0; i < 4; ++i)
            #pragma unroll
            for (int j = 0; j < 4; ++j)
                acc[i][j] = __builtin_amdgcn_mfma_f32_16x16x32_bf16(af[i], bfr[j], acc[i][j], 0, 0, 0);
        __syncthreads();
    }

    float bj[4];
    #pragma unroll
    for (int j = 0; j < 4; ++j) bj[j] = bias[n0 + wn * 64 + j * 16 + lr];
    #pragma unroll
    for (int i = 0; i < 4; ++i)
        #pragma unroll
        for (int j = 0; j < 4; ++j) {
            int col = n0 + wn * 64 + j * 16 + lr;
            #pragma unroll
            for (int r = 0; r < 4; ++r) {
                int row = m0 + wm * 64 + i * 16 + lg * 4 + r;
                outb[(size_t)row * Nd + col] = f2bf(acc[i][j][r] + bj[j]);
            }
        }
}

// ------------------------------------------------ proj GEMM + fused window-reverse/unshift/residual
__global__ __launch_bounds__(256) void k_gemm_proj(const unsigned short* __restrict__ A,
                                                   const unsigned short* __restrict__ W,
                                                   const float* __restrict__ bias,
                                                   const unsigned short* __restrict__ xres,
                                                   unsigned short* __restrict__ xs) {
    __shared__ unsigned short As[128 * 32];
    __shared__ unsigned short Bs[128 * 32];
    constexpr int K = 256;
    int t = threadIdx.x;
    int l = t & 63, w = t >> 6;
    int wm = w & 1, wn = w >> 1;
    int m0 = blockIdx.x * 128, n0 = blockIdx.y * 128;
    int lr = l & 15, lg = l >> 4;

    int row0, ch0, row1, ch1;
    inv_swz(w * 128 + l, row0, ch0);
    inv_swz(w * 128 + 64 + l, row1, ch1);
    const unsigned short* gA0 = A + (size_t)(m0 + row0) * K + ch0 * 8;
    const unsigned short* gA1 = A + (size_t)(m0 + row1) * K + ch1 * 8;
    const unsigned short* gB0 = W + (size_t)(n0 + row0) * K + ch0 * 8;
    const unsigned short* gB1 = W + (size_t)(n0 + row1) * K + ch1 * 8;
    unsigned short* lA0 = &As[(w * 128) * 8];
    unsigned short* lA1 = &As[(w * 128 + 64) * 8];
    unsigned short* lB0 = &Bs[(w * 128) * 8];
    unsigned short* lB1 = &Bs[(w * 128 + 64) * 8];

    f32x4 acc[4][4];
    #pragma unroll
    for (int i = 0; i < 4; ++i)
        #pragma unroll
        for (int j = 0; j < 4; ++j)
            acc[i][j] = (f32x4){0.f, 0.f, 0.f, 0.f};

    for (int kt = 0; kt < K; kt += 32) {
        gload_lds16(gA0 + kt, lA0);
        gload_lds16(gA1 + kt, lA1);
        gload_lds16(gB0 + kt, lB0);
        gload_lds16(gB1 + kt, lB1);
        __syncthreads();
        bf16x8 af[4], bfr[4];
        #pragma unroll
        for (int i = 0; i < 4; ++i) {
            int ra = wm * 64 + i * 16 + lr;
            af[i] = *(bf16x8*)&As[(ra * 32 + lg * 8) ^ ((ra & 7) << 3)];
            int rb = wn * 64 + i * 16 + lr;
            bfr[i] = *(bf16x8*)&Bs[(rb * 32 + lg * 8) ^ ((rb & 7) << 3)];
        }
        #pragma unroll
        for (int i = 0; i < 4; ++i)
            #pragma unroll
            for (int j = 0; j < 4; ++j)
                acc[i][j] = __builtin_amdgcn_mfma_f32_16x16x32_bf16(af[i], bfr[j], acc[i][j], 0, 0, 0);
        __syncthreads();
    }

    float bj[4];
    #pragma unroll
    for (int j = 0; j < 4; ++j) bj[j] = bias[n0 + wn * 64 + j * 16 + lr];
    #pragma unroll
    for (int i = 0; i < 4; ++i)
        #pragma unroll
        for (int j = 0; j < 4; ++j) {
            int col = n0 + wn * 64 + j * 16 + lr;
            #pragma unroll
            for (int r = 0; r < 4; ++r) {
                int row = m0 + wm * 64 + i * 16 + lg * 4 + r;   // group-local window row
                int wl = row / NTOK, tok = row - wl * NTOK;
                int bg = wl >> 6, wi = wl & 63;
                int hr = (wi >> 3) * 7 + tok / 7;
                int wr = (wi & 7) * 7 + tok % 7;
                int hh = hr + SSc; if (hh >= Hc) hh -= Hc;
                int ww = wr + SSc; if (ww >= Wc) ww -= Wc;
                size_t didx = ((size_t)bg * Lc + hh * Wc + ww) * Cc + col;
                float res = bf2f(xres[didx]);
                xs[didx] = f2bf(res + acc[i][j][r] + bj[j]);
            }
        }
}

// ------------------------------------------------ window attention v3: MFMA, 1 wave per (window, head)
__global__ __launch_bounds__(256) void k_attn(const unsigned short* __restrict__ qkv,
                                              const float* __restrict__ rpb,
                                              unsigned short* __restrict__ outb) {
    __shared__ unsigned short lds[4 * 6144 + 1352];
    unsigned short* rpbs = &lds[4 * 6144];
    int t = threadIdx.x;
    int w = t >> 6, l = t & 63;
    int lr = l & 15, lg = l >> 4;
    unsigned short* wl = &lds[w * 6144];
    unsigned short* Qs = wl;
    unsigned short* Ks = wl + 2048;
    unsigned short* Pm = wl;            // overlays Q/K after QK MFMA
    unsigned short* Vt = wl + 4096;

    for (int i = t; i < 1352; i += 256) rpbs[i] = f2bf(rpb[i]);

    int gid = blockIdx.x * 4 + w;
    int b_ = gid >> 3, hh = gid & 7;
    const unsigned short* base = qkv + (size_t)b_ * NTOK * 768 + hh * HDc;

    {
        int j = l;
        u16x8 vq[4], vk[4], vv[4];
        if (j < NTOK) {
            const unsigned short* rp = base + j * 768;
            #pragma unroll
            for (int s = 0; s < 4; ++s) {
                vq[s] = *(const u16x8*)(rp + s * 8);
                vk[s] = *(const u16x8*)(rp + 256 + s * 8);
                vv[s] = *(const u16x8*)(rp + 512 + s * 8);
            }
        } else {
            u16x8 z = {0, 0, 0, 0, 0, 0, 0, 0};
            #pragma unroll
            for (int s = 0; s < 4; ++s) { vq[s] = z; vk[s] = z; vv[s] = z; }
        }
        #pragma unroll
        for (int s = 0; s < 4; ++s) {
            int off = (j * 32 + s * 8) ^ ((j & 7) << 3);
            *(u16x8*)&Qs[off] = vq[s];
            *(u16x8*)&Ks[off] = vk[s];
        }
        #pragma unroll
        for (int s = 0; s < 4; ++s)
            #pragma unroll
            for (int e = 0; e < 8; ++e) {
                int d = s * 8 + e;
                Vt[d * 64 + (j ^ ((d & 7) << 3))] = ((unsigned short*)&vv[s])[e];
            }
    }
    __syncthreads();

    bf16x8 aq[4], bk[4];
    #pragma unroll
    for (int mt = 0; mt < 4; ++mt) {
        int row = mt * 16 + lr;
        int off = (row * 32 + lg * 8) ^ ((row & 7) << 3);
        aq[mt] = *(bf16x8*)&Qs[off];
        bk[mt] = *(bf16x8*)&Ks[off];
    }
    f32x4 sc[4][4];
    #pragma unroll
    for (int mt = 0; mt < 4; ++mt)
        #pragma unroll
        for (int nt = 0; nt < 4; ++nt)
            sc[mt][nt] = __builtin_amdgcn_mfma_f32_16x16x32_bf16(
                aq[mt], bk[nt], (f32x4){0.f, 0.f, 0.f, 0.f}, 0, 0, 0);

    const float scale = 0.17677669529663687f;
    int wi = b_ & 63, wh = wi >> 3, wwc = wi & 7;
    int jh[4], jw[4], ridJ[4];
    #pragma unroll
    for (int nt = 0; nt < 4; ++nt) {
        int j = nt * 16 + lr;
        jh[nt] = j / 7; jw[nt] = j - jh[nt] * 7;
        int gh = wh * 7 + jh[nt], gw = wwc * 7 + jw[nt];
        int rh = gh < 49 ? 0 : (gh < 53 ? 1 : 2);
        int rw = gw < 49 ? 0 : (gw < 53 ? 1 : 2);
        ridJ[nt] = rh * 3 + rw;
    }

    float rowrcp[4][4];
    #pragma unroll
    for (int mt = 0; mt < 4; ++mt) {
        #pragma unroll
        for (int r = 0; r < 4; ++r) {
            int i = mt * 16 + lg * 4 + r;
            int ih = i / 7, iw = i - ih * 7;
            int gh = wh * 7 + ih, gw = wwc * 7 + iw;
            int rhI = gh < 49 ? 0 : (gh < 53 ? 1 : 2);
            int rwI = gw < 49 ? 0 : (gw < 53 ? 1 : 2);
            int ridI = rhI * 3 + rwI;
            bool ivalid = (i < NTOK);
            float vals[4];
            float vmax = -1e30f;
            #pragma unroll
            for (int nt = 0; nt < 4; ++nt) {
                int j = nt * 16 + lr;
                float v = -1e30f;
                if (ivalid && j < NTOK) {
                    int rpi = (ih - jh[nt] + 6) * 13 + (iw - jw[nt] + 6);
                    float bv = bf2f(rpbs[rpi * 8 + hh]);
                    float msk = (ridI == ridJ[nt]) ? 0.f : -100.f;
                    v = sc[mt][nt][r] * scale + bv + msk;
                }
                vals[nt] = v;
                vmax = fmaxf(vmax, v);
            }
            #pragma unroll
            for (int off = 1; off < 16; off <<= 1)
                vmax = fmaxf(vmax, __shfl_xor(vmax, off));
            float s = 0.f;
            unsigned short pb[4];
            #pragma unroll
            for (int nt = 0; nt < 4; ++nt) {
                float e = (vals[nt] > -1e29f) ? __expf(vals[nt] - vmax) : 0.f;
                s += e;
                pb[nt] = f2bf(e);
            }
            #pragma unroll
            for (int off = 1; off < 16; off <<= 1)
                s += __shfl_xor(s, off);
            rowrcp[mt][r] = 1.f / s;
            #pragma unroll
            for (int nt = 0; nt < 4; ++nt) {
                int j = nt * 16 + lr;
                Pm[(i * 64 + j) ^ ((i & 7) << 3)] = pb[nt];
            }
        }
    }

    f32x4 o[4][2];
    #pragma unroll
    for (int mt = 0; mt < 4; ++mt)
        #pragma unroll
        for (int nt = 0; nt < 2; ++nt)
            o[mt][nt] = (f32x4){0.f, 0.f, 0.f, 0.f};
    #pragma unroll
    for (int ks = 0; ks < 2; ++ks) {
        bf16x8 ap[4], bv2[2];
        #pragma unroll
        for (int mt = 0; mt < 4; ++mt) {
            int row = mt * 16 + lr;
            ap[mt] = *(bf16x8*)&Pm[(row * 64 + ks * 32 + lg * 8) ^ ((row & 7) << 3)];
        }
        #pragma unroll
        for (int nt = 0; nt < 2; ++nt) {
            int n = nt * 16 + lr;
            bv2[nt] = *(bf16x8*)&Vt[(n * 64 + ks * 32 + lg * 8) ^ ((n & 7) << 3)];
        }
        #pragma unroll
        for (int mt = 0; mt < 4; ++mt)
            #pragma unroll
            for (int nt = 0; nt < 2; ++nt)
                o[mt][nt] = __builtin_amdgcn_mfma_f32_16x16x32_bf16(ap[mt], bv2[nt], o[mt][nt], 0, 0, 0);
    }

    #pragma unroll
    for (int mt = 0; mt < 4; ++mt)
        #pragma unroll
        for (int r = 0; r < 4; ++r) {
            int i = mt * 16 + lg * 4 + r;
            if (i < NTOK) {
                float rc = rowrcp[mt][r];
                #pragma unroll
                for (int nt = 0; nt < 2; ++nt) {
                    int d = nt * 16 + lr;
                    outb[((size_t)b_ * NTOK + i) * Cc + hh * HDc + d] = f2bf(o[mt][nt][r] * rc);
                }
            }
        }
}

// ------------------------------------------------ fused LN2 + MLP v5 + residual + NCHW out
// 128 rows/block, 512 threads. v5: fc1 computes D[h][m] (transposed) so hid writes are
// 4 packed b64 per wave per chunk instead of 16 scalar b16. hid content/layout unchanged.
#define HIDX(m, c) (((m) * 64 + (c)) ^ (((m) & 7) << 3))
__global__ __launch_bounds__(512) void k_mlp_fused(const unsigned short* __restrict__ xs,
                                                   const float* __restrict__ n2w,
                                                   const float* __restrict__ n2b,
                                                   const unsigned short* __restrict__ w1t,
                                                   const float* __restrict__ b1,
                                                   const unsigned short* __restrict__ w2t,
                                                   const float* __restrict__ b2,
                                                   float* __restrict__ out) {
    __shared__ unsigned short w1s[16384];
    __shared__ unsigned short w2s[16384];
    __shared__ unsigned short hid[8192];
    int t = threadIdx.x;
    int l = t & 63, w = t >> 6;
    int wm = w >> 1, wn = w & 1;
    int lr = l & 15, lg = l >> 4;
    int m0 = blockIdx.x * 128;

    // ---- Phase A (registers only): load 2 rows/lane, LN2, build bf16 A-frags
    bf16x8 xf[2][8];
    {
        #pragma unroll
        for (int mf = 0; mf < 2; ++mf) {
            int row = m0 + wm * 32 + mf * 16 + lr;
            const unsigned short* xrow = xs + (size_t)row * Cc;
            u16x8 raw[8];
            float sum = 0.f, sq = 0.f;
            #pragma unroll
            for (int ks = 0; ks < 8; ++ks) {
                raw[ks] = *(const u16x8*)(xrow + ks * 32 + lg * 8);
                #pragma unroll
                for (int e = 0; e < 8; ++e) {
                    float f = bf2f(raw[ks][e]);
                    sum += f; sq += f * f;
                }
            }
            sum += __shfl_xor(sum, 16); sq += __shfl_xor(sq, 16);
            sum += __shfl_xor(sum, 32); sq += __shfl_xor(sq, 32);
            float mu = sum / Cc;
            float rsg = rsqrtf(sq / Cc - mu * mu + EPS);
            #pragma unroll
            for (int ks = 0; ks < 8; ++ks) {
                #pragma unroll
                for (int e = 0; e < 8; ++e) {
                    int c = ks * 32 + lg * 8 + e;
                    float nv = (bf2f(raw[ks][e]) - mu) * rsg * n2w[c] + n2b[c];
                    ((unsigned short*)&xf[mf][ks])[e] = f2bf(nv);
                }
            }
        }
    }

    f32x4 acc2[2][8];
    #pragma unroll
    for (int mf = 0; mf < 2; ++mf)
        #pragma unroll
        for (int nf = 0; nf < 8; ++nf)
            acc2[mf][nf] = (f32x4){0.f, 0.f, 0.f, 0.f};

    // prefetch chunk 0
    u16x8 p1[4], p2[4];
    #pragma unroll
    for (int i = 0; i < 4; ++i) {
        int idx = (i * 512 + t) * 8;
        p1[i] = *(const u16x8*)(w1t + idx);
        p2[i] = *(const u16x8*)(w2t + idx);
    }

    for (int ch = 0; ch < 16; ++ch) {
        #pragma unroll
        for (int i = 0; i < 4; ++i) {
            int idx = (i * 512 + t) * 8;
            *(u16x8*)&w1s[idx] = p1[i];
            *(u16x8*)&w2s[idx] = p2[i];
        }
        __syncthreads();
        if (ch < 15) {
            const unsigned short* n1 = w1t + (ch + 1) * 16384;
            const unsigned short* n2 = w2t + (ch + 1) * 16384;
            #pragma unroll
            for (int i = 0; i < 4; ++i) {
                int idx = (i * 512 + t) * 8;
                p1[i] = *(const u16x8*)(n1 + idx);
                p2[i] = *(const u16x8*)(n2 + idx);
            }
        }
        // ---- fc1 (transposed): D[h][m]; wave (wm,wn): h-tiles {2wn, 2wn+1}, m-tiles {2wm, 2wm+1}
        {
            f32x4 acc1[2][2];
            #pragma unroll
            for (int ht = 0; ht < 2; ++ht)
                #pragma unroll
                for (int mf = 0; mf < 2; ++mf)
                    acc1[ht][mf] = (f32x4){0.f, 0.f, 0.f, 0.f};
            #pragma unroll
            for (int ks = 0; ks < 8; ++ks) {
                bf16x8 wfr[2];
                #pragma unroll
                for (int ht = 0; ht < 2; ++ht)
                    wfr[ht] = *(const bf16x8*)&w1s[(wn * 2 + ht) * 4096 + ks * 512 + l * 8];
                #pragma unroll
                for (int ht = 0; ht < 2; ++ht) {
                    acc1[ht][0] = __builtin_amdgcn_mfma_f32_16x16x32_bf16(wfr[ht], xf[0][ks], acc1[ht][0], 0, 0, 0);
                    acc1[ht][1] = __builtin_amdgcn_mfma_f32_16x16x32_bf16(wfr[ht], xf[1][ks], acc1[ht][1], 0, 0, 0);
                }
            }
            #pragma unroll
            for (int ht = 0; ht < 2; ++ht) {
                float b1v[4];
                #pragma unroll
                for (int r = 0; r < 4; ++r)
                    b1v[r] = b1[ch * 64 + (wn * 2 + ht) * 16 + lg * 4 + r];
                #pragma unroll
                for (int mf = 0; mf < 2; ++mf) {
                    u16x4 pk;
                    #pragma unroll
                    for (int r = 0; r < 4; ++r)
                        pk[r] = f2bf(fmaxf(acc1[ht][mf][r] + b1v[r], 0.f));
                    int m = wm * 32 + mf * 16 + lr;
                    int off = m * 64 + ((((wn * 2 + ht) * 16) + lg * 4) ^ ((m & 7) << 3));
                    *(u16x4*)&hid[off] = pk;
                }
            }
        }
        __syncthreads();
        // ---- fc2 partial over this chunk's 64 h-dims
        {
            bf16x8 a[2][2];
            #pragma unroll
            for (int mf = 0; mf < 2; ++mf)
                #pragma unroll
                for (int ks = 0; ks < 2; ++ks) {
                    int m = wm * 32 + mf * 16 + lr;
                    a[mf][ks] = *(const bf16x8*)&hid[HIDX(m, ks * 32 + lg * 8)];
                }
            #pragma unroll
            for (int ks = 0; ks < 2; ++ks)
                #pragma unroll
                for (int nf = 0; nf < 8; ++nf) {
                    int nt = (wn * 128 + nf * 16) >> 4;
                    bf16x8 bfr = *(const bf16x8*)&w2s[(nt * 2 + ks) * 512 + l * 8];
                    acc2[0][nf] = __builtin_amdgcn_mfma_f32_16x16x32_bf16(a[0][ks], bfr, acc2[0][nf], 0, 0, 0);
                    acc2[1][nf] = __builtin_amdgcn_mfma_f32_16x16x32_bf16(a[1][ks], bfr, acc2[1][nf], 0, 0, 0);
                }
        }
        __syncthreads();
    }

    // ---- epilogue: + b2 + residual, NCHW store
    int b0i = m0 / Lc, l0 = m0 % Lc;
    #pragma unroll
    for (int nf = 0; nf < 8; ++nf) {
        int c = wn * 128 + nf * 16 + lr;
        float b2c = b2[c];
        #pragma unroll
        for (int mf = 0; mf < 2; ++mf)
            #pragma unroll
            for (int r = 0; r < 4; ++r) {
                int m = wm * 32 + mf * 16 + lg * 4 + r;
                float res = bf2f(xs[(size_t)(m0 + m) * Cc + c]);
                int lm = l0 + m;
                int bi = b0i + (lm >= Lc);
                if (lm >= Lc) lm -= Lc;
                out[((size_t)bi * Cc + c) * Lc + lm] = acc2[mf][nf][r] + b2c + res;
            }
    }
}

// ----------------------------------------------------------------- launch
extern "C" void kernel_launch(void* const* d_in, const int* in_sizes, int n_in,
                              void* d_out, int out_size, void* d_ws, size_t ws_size,
                              hipStream_t stream) {
    const float* x      = (const float*)d_in[0];
    const float* qkv_w  = (const float*)d_in[1];
    const float* q_bias = (const float*)d_in[2];
    const float* v_bias = (const float*)d_in[3];
    const float* proj_w = (const float*)d_in[4];
    const float* proj_b = (const float*)d_in[5];
    const float* rpb    = (const float*)d_in[6];
    const float* n1w    = (const float*)d_in[7];
    const float* n1b    = (const float*)d_in[8];
    const float* n2w    = (const float*)d_in[9];
    const float* n2b    = (const float*)d_in[10];
    const float* w1     = (const float*)d_in[11];
    const float* b1     = (const float*)d_in[12];
    const float* w2     = (const float*)d_in[13];
    const float* b2     = (const float*)d_in[14];

    char* ws = (char*)d_ws;
    const size_t SZ_BF16 = (size_t)Mrows * Cc * 2;
    unsigned short* xw      = (unsigned short*)ws;          // xw, later xs (b,l,c)
    float*          qkvb    = (float*)(ws + SZ_BF16);
    unsigned short* qkv_wb  = (unsigned short*)(ws + SZ_BF16 + 3072);
    unsigned short* proj_wb = qkv_wb + 196608;
    unsigned short* w1t     = proj_wb + 65536;
    unsigned short* w2t     = w1t + 262144;

    unsigned short* qkv_s  = (unsigned short*)d_out;
    unsigned short* attn_s = qkv_s + (size_t)ROWS_G * 768;
    unsigned short* xres_s = attn_s + (size_t)ROWS_G * Cc;

    k_prep<<<1024, 256, 0, stream>>>(qkv_w, proj_w, w1, w2, q_bias, v_bias,
                                     qkv_wb, proj_wb, w1t, w2t, qkvb);

    for (int g = 0; g < NGRP; ++g) {
        unsigned short* xw_g = xw + (size_t)g * ROWS_G * Cc;
        k_ln1_part<<<GIMG * Hc, 256, 0, stream>>>(x, n1w, n1b, xw, xres_s, g * GIMG);
        k_gemm_mfma<<<dim3(ROWS_G / 128, 768 / 128), 256, 0, stream>>>(
            xw_g, qkv_wb, qkvb, qkv_s, 256, 768);
        k_attn<<<WIN_G * NHc / 4, 256, 0, stream>>>(qkv_s, rpb, attn_s);
        k_gemm_proj<<<dim3(ROWS_G / 128, 2), 256, 0, stream>>>(
            attn_s, proj_wb, proj_b, xres_s, xw_g);
    }

    k_mlp_fused<<<Mrows / 128, 512, 0, stream>>>(xw, n2w, n2b, w1t, b1, w2t, b2,
                                                 (float*)d_out);
}